// Round 1
// baseline (1415.785 us; speedup 1.0000x reference)
//
#include <hip/hip_runtime.h>
#include <hip/hip_bf16.h>
#include <math.h>

#define L     16384
#define IMG   128
#define BATCH 2
#define C0    192
#define NH    4
#define CHN   48
#define HID   510
#define HID2  1020
#define BL    (BATCH*L)

typedef __hip_bfloat16 bf16;

__device__ __forceinline__ float b2f(bf16 v){ return __bfloat162float(v); }
__device__ __forceinline__ bf16  f2b(float v){ return __float2bfloat16(v); }
__device__ __forceinline__ float gelu_exact(float x){ return 0.5f*x*(1.0f+erff(x*0.70710678118654752f)); }

// per-position channel-LN stats: mu, rsig over C0 channels
__global__ __launch_bounds__(256) void ln_stats_k(const float* __restrict__ x,
                                                  float* __restrict__ mu, float* __restrict__ rsig){
  int pos = blockIdx.x*256 + threadIdx.x;          // [0, BATCH*L)
  int b = pos >> 14, l = pos & (L-1);
  const float* xp = x + (size_t)b*C0*L + l;
  float s=0.f, ss=0.f;
  for (int c=0;c<C0;++c){ float v = xp[(size_t)c*L]; s += v; ss += v*v; }
  float m = s*(1.f/C0);
  float var = ss*(1.f/C0) - m*m;
  mu[pos]=m; rsig[pos]=rsqrtf(var + 1e-5f);
}

// Wt[c][o] = W[o][c] * lnw[c]  (zero-padded to Opad)
__global__ void wtrans_k(const float* __restrict__ W, const float* __restrict__ lnw,
                         float* __restrict__ Wt, int Cc, int O, int Opad){
  int idx = blockIdx.x*256 + threadIdx.x;
  if (idx >= Cc*Opad) return;
  int c = idx / Opad, o = idx % Opad;
  float v = 0.f;
  if (o < O){ v = W[(size_t)o*Cc + c]; if (lnw) v *= lnw[c]; }
  Wt[idx] = v;
}

// A[o] = sum_c W[o,c]*lnw[c];  B[o] = sum_c W[o,c]*lnb[c]
__global__ void prepab_k(const float* __restrict__ W, const float* __restrict__ lnw,
                         const float* __restrict__ lnb, float* __restrict__ A, float* __restrict__ Bv,
                         int Cc, int O, int Opad){
  int o = blockIdx.x*256 + threadIdx.x;
  if (o >= Opad) return;
  float a=0.f,b=0.f;
  if (o < O){
    const float* wr = W + (size_t)o*Cc;
    for (int c=0;c<Cc;++c){ float w=wr[c]; a = fmaf(w, lnw[c], a); b = fmaf(w, lnb[c], b); }
  }
  A[o]=a; Bv[o]=b;
}

// fused channel-LN + 1x1 conv: out[o,pos] = rsig*(sum_c G[c][o]*x[c,pos] - mu*A[o]) + B[o]  (bf16 out)
__global__ __launch_bounds__(256) void convln_k(const float* __restrict__ x, const float* __restrict__ Wt,
    const float* __restrict__ A, const float* __restrict__ Bv,
    const float* __restrict__ mu, const float* __restrict__ rsig,
    bf16* __restrict__ out, int Cc, int O, int Opad){
  int pos = blockIdx.x*256 + threadIdx.x;
  int b = pos >> 14, l = pos & (L-1);
  int obase = blockIdx.y*64;
  const float* xp = x + (size_t)b*Cc*L + l;
  float acc[64];
  #pragma unroll
  for (int j=0;j<64;++j) acc[j]=0.f;
  for (int c=0;c<Cc;++c){
    float xv = xp[(size_t)c*L];
    const float* wr = Wt + (size_t)c*Opad + obase;
    #pragma unroll
    for (int j=0;j<64;++j) acc[j] = fmaf(wr[j], xv, acc[j]);
  }
  float m = mu[pos], rs = rsig[pos];
  bf16* op = out + (size_t)b*O*L + l;
  #pragma unroll
  for (int j=0;j<64;++j){
    int o = obase + j;
    if (o < O) op[(size_t)o*L] = f2b(rs*(acc[j] - m*A[o]) + Bv[o]);
  }
}

// depthwise 3x3 (SAME, zero pad), bf16 in/out, optional sum-of-squares per (b,channel) row
__global__ __launch_bounds__(256) void dwconv_k(const bf16* __restrict__ in, const float* __restrict__ w9,
    bf16* __restrict__ out, float* __restrict__ ss, int Cc, int nss){
  int e = blockIdx.x*256 + threadIdx.x;      // [0, BATCH*Cc*L)
  int p = e & (L-1); int bc = e >> 14;
  int c = bc % Cc; int b = bc / Cc;
  int y = p >> 7, xx = p & (IMG-1);
  const float* wp = w9 + c*9;
  const bf16* ip = in + (size_t)bc*L;
  float acc=0.f;
  #pragma unroll
  for (int dy=-1;dy<=1;++dy){
    int yy=y+dy; if ((unsigned)yy>=IMG) continue;
    #pragma unroll
    for (int dx=-1;dx<=1;++dx){
      int xw=xx+dx; if ((unsigned)xw>=IMG) continue;
      acc = fmaf(wp[(dy+1)*3+(dx+1)], b2f(ip[yy*IMG+xw]), acc);
    }
  }
  out[(size_t)bc*L + p] = f2b(acc);
  if (ss != nullptr && c < nss){
    float v = acc*acc;
    #pragma unroll
    for (int off=32; off>0; off>>=1) v += __shfl_xor(v, off, 64);
    __shared__ float red[4];
    int wid = threadIdx.x >> 6;
    if ((threadIdx.x & 63)==0) red[wid]=v;
    __syncthreads();
    if (threadIdx.x==0) atomicAdd(&ss[b*nss + c], red[0]+red[1]+red[2]+red[3]);
  }
}

// raw QK^T: one block per (b,h,c,d), dot over L
__global__ __launch_bounds__(256) void qk_k(const bf16* __restrict__ q, const bf16* __restrict__ kv,
                                            float* __restrict__ S){
  int blk = blockIdx.x;                      // ((b*NH+h)*CHN+c)*CHN+d
  int d = blk % CHN; int t2 = blk / CHN;
  int c = t2 % CHN; t2 /= CHN;
  int h = t2 % NH;  int b = t2 / NH;
  const bf16* qp = q  + ((size_t)b*C0     + h*CHN + c)*L;
  const bf16* kp = kv + ((size_t)b*(2*C0) + h*CHN + d)*L;
  float s=0.f;
  for (int i=threadIdx.x; i<L; i+=256) s = fmaf(b2f(qp[i]), b2f(kp[i]), s);
  #pragma unroll
  for (int off=32; off>0; off>>=1) s += __shfl_xor(s, off, 64);
  __shared__ float red[4];
  int wid = threadIdx.x >> 6;
  if ((threadIdx.x & 63)==0) red[wid]=s;
  __syncthreads();
  if (threadIdx.x==0) S[blk] = red[0]+red[1]+red[2]+red[3];
}

// softmax + relu^2/gelu gating + Wca modulation -> final attention [b,h,48,48]
__global__ void gating_k(const float* __restrict__ S, const float* __restrict__ qss,
                         const float* __restrict__ kss, const float* __restrict__ temp,
                         const float* __restrict__ Wca, float* __restrict__ attnF){
  int bh = blockIdx.x; int h = bh % NH; int b = bh / NH;
  int t = threadIdx.x;
  __shared__ float rk[CHN], rqv[CHN];
  if (t < CHN){
    float nk = sqrtf(kss[b*C0 + h*CHN + t]); rk[t]  = 1.f/fmaxf(nk, 1e-12f);
    float nq = sqrtf(qss[b*C0 + h*CHN + t]); rqv[t] = 1.f/fmaxf(nq, 1e-12f);
  }
  __syncthreads();
  if (t >= CHN) return;
  float T = temp[h];
  float rq = rqv[t];
  const float* Srow = S + ((size_t)bh*CHN + t)*CHN;
  float raw[CHN], a0[CHN], a1[CHN];
  float mx = -1e30f;
  for (int d=0;d<CHN;++d){ raw[d] = Srow[d]*rq*rk[d]*T; mx = fmaxf(mx, raw[d]); }
  float sum=0.f;
  for (int d=0;d<CHN;++d){ a0[d] = expf(raw[d]-mx); sum += a0[d]; }
  float inv = 1.f/sum;
  for (int d=0;d<CHN;++d){
    float r = fmaxf(raw[d],0.f); r = r*r;
    a1[d] = gelu_exact(r)*r;
  }
  float* outr = attnF + ((size_t)bh*CHN + t)*CHN;
  for (int d=0;d<CHN;++d){
    float s1=0.f, s2=0.f;
    const float* w1 = Wca + (size_t)d*CHN;
    const float* w2 = Wca + (size_t)(d+CHN)*CHN;
    for (int j=0;j<CHN;++j){ s1 = fmaf(w1[j], a1[j], s1); s2 = fmaf(w2[j], a1[j], s2); }
    outr[d] = a0[d]*inv*(1.f+s1) + s2;
  }
}

// M[b][dfull][o] = sum_c Wproj[o][h*48+c] * attnF[b][h][c][d]   (fold attn@V with Wproj)
__global__ void mt_k(const float* __restrict__ Wproj, const float* __restrict__ attnF,
                     float* __restrict__ Mt){
  int idx = blockIdx.x*256 + threadIdx.x;
  if (idx >= BATCH*C0*C0) return;
  int o = idx % C0; int dfull = (idx / C0) % C0; int b = idx / (C0*C0);
  int h = dfull / CHN, d = dfull % CHN;
  float s=0.f;
  for (int c=0;c<CHN;++c)
    s = fmaf(Wproj[(size_t)o*C0 + h*CHN + c],
             attnF[(((size_t)(b*NH+h))*CHN + c)*CHN + d], s);
  Mt[((size_t)b*C0 + dfull)*C0 + o] = s;
}

// lr2[o,pos] = lr[o,pos] + sum_d Mt[b][d][o] * v[d,pos]   (fp32 out = d_out)
__global__ __launch_bounds__(256) void proj_k(const float* __restrict__ lr, const bf16* __restrict__ kv,
                                              const float* __restrict__ Mt, float* __restrict__ out){
  int pos = blockIdx.x*256 + threadIdx.x;
  int b = pos >> 14, l = pos & (L-1);
  int obase = blockIdx.y*64;
  const bf16* vp = kv + ((size_t)b*(2*C0) + C0)*L + l;
  const float* Mb = Mt + (size_t)b*C0*C0;
  float acc[64];
  #pragma unroll
  for (int j=0;j<64;++j) acc[j]=0.f;
  for (int d=0;d<C0;++d){
    float xv = b2f(vp[(size_t)d*L]);
    const float* wr = Mb + (size_t)d*C0 + obase;
    #pragma unroll
    for (int j=0;j<64;++j) acc[j] = fmaf(wr[j], xv, acc[j]);
  }
  const float* lp = lr + (size_t)b*C0*L + l;
  float* op = out + (size_t)b*C0*L + l;
  #pragma unroll
  for (int j=0;j<64;++j){ int o=obase+j; op[(size_t)o*L] = lp[(size_t)o*L] + acc[j]; }
}

// fused dwconv3x3 + gelu gate for GDFN: g[go] = gelu(dw(h[go])) * dw(h[go+510])
__global__ __launch_bounds__(256) void ffn_k(const bf16* __restrict__ hidden, const float* __restrict__ w9,
                                             bf16* __restrict__ g){
  int e = blockIdx.x*256 + threadIdx.x;      // [0, BATCH*HID*L)
  int p = e & (L-1); int bg = e >> 14;
  int go = bg % HID; int b = bg / HID;
  int y = p>>7, xx = p&(IMG-1);
  const bf16* i1 = hidden + ((size_t)b*HID2 + go)*L;
  const bf16* i2 = hidden + ((size_t)b*HID2 + HID + go)*L;
  const float* w1 = w9 + (size_t)go*9;
  const float* w2 = w9 + (size_t)(HID+go)*9;
  float d1=0.f, d2=0.f;
  #pragma unroll
  for (int dy=-1;dy<=1;++dy){
    int yy=y+dy; if ((unsigned)yy>=IMG) continue;
    #pragma unroll
    for (int dx=-1;dx<=1;++dx){
      int xw=xx+dx; if ((unsigned)xw>=IMG) continue;
      int off = yy*IMG+xw; int wo = (dy+1)*3+(dx+1);
      d1 = fmaf(w1[wo], b2f(i1[off]), d1);
      d2 = fmaf(w2[wo], b2f(i2[off]), d2);
    }
  }
  g[(size_t)bg*L + p] = f2b(gelu_exact(d1)*d2);
}

// d_out[o,pos] += sum_c WpoutT[c][o] * g[c,pos]
__global__ __launch_bounds__(256) void pout_k(const bf16* __restrict__ g, const float* __restrict__ Wt,
                                              float* __restrict__ out){
  int pos = blockIdx.x*256 + threadIdx.x;
  int b = pos >> 14, l = pos & (L-1);
  int obase = blockIdx.y*64;
  const bf16* gp = g + (size_t)b*HID*L + l;
  float acc[64];
  #pragma unroll
  for (int j=0;j<64;++j) acc[j]=0.f;
  for (int c=0;c<HID;++c){
    float xv = b2f(gp[(size_t)c*L]);
    const float* wr = Wt + (size_t)c*C0 + obase;
    #pragma unroll
    for (int j=0;j<64;++j) acc[j] = fmaf(wr[j], xv, acc[j]);
  }
  float* op = out + (size_t)b*C0*L + l;
  #pragma unroll
  for (int j=0;j<64;++j){ int o=obase+j; op[(size_t)o*L] += acc[j]; }
}

extern "C" void kernel_launch(void* const* d_in, const int* in_sizes, int n_in,
                              void* d_out, int out_size, void* d_ws, size_t ws_size,
                              hipStream_t stream){
  (void)in_sizes; (void)n_in; (void)out_size; (void)ws_size;
  const float* lr    = (const float*)d_in[0];
  const float* ref   = (const float*)d_in[1];
  const float* ln1w  = (const float*)d_in[2];
  const float* ln1b  = (const float*)d_in[3];
  const float* lnrw  = (const float*)d_in[4];
  const float* lnrb  = (const float*)d_in[5];
  const float* ln2w  = (const float*)d_in[6];
  const float* ln2b  = (const float*)d_in[7];
  const float* Wq    = (const float*)d_in[8];
  const float* qdw   = (const float*)d_in[9];
  const float* Wkv   = (const float*)d_in[10];
  const float* kvdw  = (const float*)d_in[11];
  const float* Wproj = (const float*)d_in[12];
  const float* Wca   = (const float*)d_in[13];
  const float* temp  = (const float*)d_in[14];
  const float* Wpin  = (const float*)d_in[15];
  const float* ffndw = (const float*)d_in[16];
  const float* Wpout = (const float*)d_in[17];
  float* out = (float*)d_out;

  char* ws = (char*)d_ws;
  size_t off = 0;
  auto alloc = [&](size_t bytes)->void*{ void* p = ws + off; off += (bytes + 255) & ~(size_t)255; return p; };

  float* WqT    = (float*)alloc((size_t)192*192*4);
  float* Aq     = (float*)alloc(192*4);
  float* Bq     = (float*)alloc(192*4);
  float* WkvT   = (float*)alloc((size_t)192*384*4);
  float* Akv    = (float*)alloc(384*4);
  float* Bkv    = (float*)alloc(384*4);
  float* WpinT  = (float*)alloc((size_t)192*1024*4);
  float* Apin   = (float*)alloc(1024*4);
  float* Bpin   = (float*)alloc(1024*4);
  float* WpoutT = (float*)alloc((size_t)510*192*4);
  float* Mt     = (float*)alloc((size_t)BATCH*C0*C0*4);
  float* mu_lr  = (float*)alloc((size_t)BL*4);
  float* rs_lr  = (float*)alloc((size_t)BL*4);
  float* mu_rf  = (float*)alloc((size_t)BL*4);
  float* rs_rf  = (float*)alloc((size_t)BL*4);
  float* mu_l2  = (float*)alloc((size_t)BL*4);
  float* rs_l2  = (float*)alloc((size_t)BL*4);
  float* qss    = (float*)alloc((size_t)BATCH*C0*4);
  float* kss    = (float*)alloc((size_t)BATCH*C0*4);
  float* S      = (float*)alloc((size_t)BATCH*NH*CHN*CHN*4);
  float* attnF  = (float*)alloc((size_t)BATCH*NH*CHN*CHN*4);
  bf16*  gbuf   = (bf16*) alloc((size_t)BATCH*HID*L*2);
  char*  pool   = (char*) alloc((size_t)75497472);   // q_pre | q | kv_pre | kv ; hidden overlays later
  bf16* q_pre  = (bf16*)(pool);
  bf16* qb     = (bf16*)(pool + 12582912);
  bf16* kv_pre = (bf16*)(pool + 25165824);
  bf16* kvb    = (bf16*)(pool + 50331648);
  bf16* hidden = (bf16*)(pool);                      // reused after attention phase

  hipMemsetAsync(qss, 0, (size_t)BATCH*C0*4, stream);
  hipMemsetAsync(kss, 0, (size_t)BATCH*C0*4, stream);

  // weight prep
  wtrans_k<<<(192*192+255)/256,256,0,stream>>>(Wq,   ln1w, WqT,   192, 192, 192);
  wtrans_k<<<(192*384+255)/256,256,0,stream>>>(Wkv,  lnrw, WkvT,  192, 384, 384);
  wtrans_k<<<(192*1024+255)/256,256,0,stream>>>(Wpin, ln2w, WpinT, 192, 1020, 1024);
  wtrans_k<<<(510*192+255)/256,256,0,stream>>>(Wpout, nullptr, WpoutT, 510, 192, 192);
  prepab_k<<<1,256,0,stream>>>(Wq,  ln1w, ln1b, Aq,  Bq,  192, 192, 192);
  prepab_k<<<2,256,0,stream>>>(Wkv, lnrw, lnrb, Akv, Bkv, 192, 384, 384);
  prepab_k<<<4,256,0,stream>>>(Wpin,ln2w, ln2b, Apin,Bpin,192, 1020, 1024);

  // LN stats for lr and ref
  ln_stats_k<<<BL/256,256,0,stream>>>(lr,  mu_lr, rs_lr);
  ln_stats_k<<<BL/256,256,0,stream>>>(ref, mu_rf, rs_rf);

  // fused LN + 1x1 convs
  convln_k<<<dim3(BL/256,3),256,0,stream>>>(lr,  WqT,  Aq,  Bq,  mu_lr, rs_lr, q_pre,  192, 192, 192);
  convln_k<<<dim3(BL/256,6),256,0,stream>>>(ref, WkvT, Akv, Bkv, mu_rf, rs_rf, kv_pre, 192, 384, 384);

  // depthwise convs (+ sum-of-squares for l2norm)
  dwconv_k<<<(BATCH*192*L)/256,256,0,stream>>>(q_pre,  qdw,  qb,  qss, 192, 192);
  dwconv_k<<<(BATCH*384*L)/256,256,0,stream>>>(kv_pre, kvdw, kvb, kss, 384, 192);

  // attention core
  qk_k<<<BATCH*NH*CHN*CHN,256,0,stream>>>(qb, kvb, S);
  gating_k<<<BATCH*NH,64,0,stream>>>(S, qss, kss, temp, Wca, attnF);
  mt_k<<<(BATCH*C0*C0+255)/256,256,0,stream>>>(Wproj, attnF, Mt);
  proj_k<<<dim3(BL/256,3),256,0,stream>>>(lr, kvb, Mt, out);

  // GDFN
  ln_stats_k<<<BL/256,256,0,stream>>>(out, mu_l2, rs_l2);
  convln_k<<<dim3(BL/256,16),256,0,stream>>>(out, WpinT, Apin, Bpin, mu_l2, rs_l2, hidden, 192, 1020, 1024);
  ffn_k<<<(BATCH*HID*L)/256,256,0,stream>>>(hidden, ffndw, gbuf);
  pout_k<<<dim3(BL/256,3),256,0,stream>>>(gbuf, WpoutT, out);
}

// Round 2
// 537.770 us; speedup vs baseline: 2.6327x; 2.6327x over previous
//
#include <hip/hip_runtime.h>
#include <hip/hip_bf16.h>
#include <math.h>

#define L     16384
#define IMG   128
#define BATCH 2
#define C0    192
#define NH    4
#define CHN   48
#define HID   510
#define HID2  1020
#define BL    (BATCH*L)
#define KSPLIT 128

typedef float  f32x4  __attribute__((ext_vector_type(4)));
typedef __bf16 bf16x8 __attribute__((ext_vector_type(8)));

union UB16 { uint4 u; bf16x8 v; };

__device__ __forceinline__ bf16x8 ld_bf8(const ushort* p){ UB16 x; x.u = *(const uint4*)p; return x.v; }
__device__ __forceinline__ f32x4 mfma16(bf16x8 a, bf16x8 b, f32x4 c){
  return __builtin_amdgcn_mfma_f32_16x16x32_bf16(a, b, c, 0, 0, 0);
}
__device__ __forceinline__ float u2f(ushort u){ union{unsigned u; float f;} x; x.u = ((unsigned)u)<<16; return x.f; }
__device__ __forceinline__ ushort f2u(float f){ __hip_bfloat16 h = __float2bfloat16(f); return *reinterpret_cast<ushort*>(&h); }
__device__ __forceinline__ float gelu_exact(float x){ return 0.5f*x*(1.0f+erff(x*0.70710678118654752f)); }

// ---------------- per-position channel-LN stats ----------------
__global__ __launch_bounds__(256) void ln_stats_k(const float* __restrict__ x,
                                                  float* __restrict__ mu, float* __restrict__ rsig){
  int pos = blockIdx.x*256 + threadIdx.x;
  int b = pos >> 14, l = pos & (L-1);
  const float* xp = x + (size_t)b*C0*L + l;
  float s=0.f, ss=0.f;
  for (int c=0;c<C0;++c){ float v = xp[(size_t)c*L]; s += v; ss += v*v; }
  float m = s*(1.f/C0);
  float var = ss*(1.f/C0) - m*m;
  mu[pos]=m; rsig[pos]=rsqrtf(var + 1e-5f);
}

// ---------------- weight packing (fp32 -> bf16, [Mpad][Kpad] row-major) ----------------
__global__ void packw_k(const float* __restrict__ W, const float* __restrict__ lnw,
                        ushort* __restrict__ out, int Csrc, int O, int Kpad, int total){
  int idx = blockIdx.x*256 + threadIdx.x;
  if (idx >= total) return;
  int m = idx / Kpad, k = idx - m*Kpad;
  float v = 0.f;
  if (k < Csrc && m < O){ v = W[(size_t)m*Csrc + k]; if (lnw) v *= lnw[k]; }
  out[idx] = f2u(v);
}

// A[o]=sum_c W[o,c]*lnw[c]; B[o]=sum_c W[o,c]*lnb[c]  (padded to Opad)
__global__ void prepab_k(const float* __restrict__ W, const float* __restrict__ lnw,
                         const float* __restrict__ lnb, float* __restrict__ A, float* __restrict__ Bv,
                         int Cc, int O, int Opad){
  int o = blockIdx.x*256 + threadIdx.x;
  if (o >= Opad) return;
  float a=0.f,b=0.f;
  if (o < O){
    const float* wr = W + (size_t)o*Cc;
    for (int c=0;c<Cc;++c){ float w=wr[c]; a = fmaf(w, lnw[c], a); b = fmaf(w, lnb[c], b); }
  }
  A[o]=a; Bv[o]=b;
}

// ---------------- MFMA GEMM: OUT[o,pos] = epilogue( sum_k A[o,k]*X[k,pos] ) ----------------
// A: bf16 [Mpad][Kpad] row-major. X: [b][rows][L] (bf16 or f32). Tile: M64 x N128, 4 waves.
// EPI 0: LN  -> bf16 out = rs*(acc - mu*Avec[o]) + Bvec[o]
// EPI 1: RES -> f32 out = res + acc
// EPI 2: ADD -> f32 out += acc
template<int EPI, bool BF32>
__global__ __launch_bounds__(256) void gemm_k(
    const ushort* __restrict__ A, int Kpad, int aBatchStride,
    const void* __restrict__ X, size_t xBS,
    const float* __restrict__ mu, const float* __restrict__ rs,
    const float* __restrict__ Avec, const float* __restrict__ Bvec,
    const float* __restrict__ res,
    void* __restrict__ outp, int Orows, int Ovalid)
{
  __shared__ ushort xt[128][40];
  const int tid  = threadIdx.x;
  const int lane = tid & 63, w = tid >> 6;
  const int nblk = blockIdx.x;
  const int b    = nblk >> 7;
  const int l0   = (nblk & 127) * 128;
  const int mbase= blockIdx.y * 64;
  const int g16  = lane >> 4, c16 = lane & 15;

  const ushort* Ab = A + (size_t)b * aBatchStride;

  f32x4 acc[4][2];
  #pragma unroll
  for (int mi=0; mi<4; ++mi)
    #pragma unroll
    for (int ni=0; ni<2; ++ni){ f32x4 z = {0.f,0.f,0.f,0.f}; acc[mi][ni] = z; }

  const int sc2  = (tid & 15) * 2;
  const int spos = (tid >> 4) * 8;
  const int kSteps = Kpad >> 5;

  for (int ks = 0; ks < kSteps; ++ks){
    const int kbase = ks << 5;
    // ---- load staging data (2 rows x 8 pos) + A fragments (global, L2) ----
    ushort ua[8], ub[8];
    if (BF32){
      const float* xr = (const float*)X + (size_t)b*xBS + (size_t)(kbase+sc2)*L + l0 + spos;
      float fa[8], fb[8];
      *(float4*)&fa[0] = *(const float4*)xr;       *(float4*)&fa[4] = *(const float4*)(xr+4);
      *(float4*)&fb[0] = *(const float4*)(xr+L);   *(float4*)&fb[4] = *(const float4*)(xr+L+4);
      #pragma unroll
      for (int j=0;j<8;++j){ ua[j]=f2u(fa[j]); ub[j]=f2u(fb[j]); }
    } else {
      const ushort* xr = (const ushort*)X + (size_t)b*xBS + (size_t)(kbase+sc2)*L + l0 + spos;
      uint4 ra = *(const uint4*)xr; uint4 rb = *(const uint4*)(xr+L);
      const ushort* pa = (const ushort*)&ra; const ushort* pb = (const ushort*)&rb;
      #pragma unroll
      for (int j=0;j<8;++j){ ua[j]=pa[j]; ub[j]=pb[j]; }
    }
    bf16x8 af[4];
    #pragma unroll
    for (int mi=0; mi<4; ++mi)
      af[mi] = ld_bf8(Ab + (size_t)(mbase + mi*16 + c16)*Kpad + kbase + g16*8);

    __syncthreads();
    #pragma unroll
    for (int j=0;j<8;++j){ ushort2 t2; t2.x = ua[j]; t2.y = ub[j]; *(ushort2*)&xt[spos+j][sc2] = t2; }
    __syncthreads();

    bf16x8 bv[2];
    #pragma unroll
    for (int ni=0; ni<2; ++ni)
      bv[ni] = ld_bf8(&xt[w*32 + ni*16 + c16][g16*8]);
    #pragma unroll
    for (int mi=0; mi<4; ++mi)
      #pragma unroll
      for (int ni=0; ni<2; ++ni)
        acc[mi][ni] = mfma16(af[mi], bv[ni], acc[mi][ni]);
  }

  // ---- epilogue ----
  const int rowOff = g16*4;
  #pragma unroll
  for (int ni=0; ni<2; ++ni){
    int nl = w*32 + ni*16 + c16;
    int l  = l0 + nl;
    float muv=0.f, rsv=0.f;
    if (EPI == 0){ int pos = b*L + l; muv = mu[pos]; rsv = rs[pos]; }
    #pragma unroll
    for (int mi=0; mi<4; ++mi){
      #pragma unroll
      for (int r=0; r<4; ++r){
        int o = mbase + mi*16 + rowOff + r;
        float a = acc[mi][ni][r];
        if (EPI == 0){
          if (o < Ovalid){
            float vv = rsv*(a - muv*Avec[o]) + Bvec[o];
            ((ushort*)outp)[((size_t)b*Orows + o)*L + l] = f2u(vv);
          }
        } else if (EPI == 1){
          size_t idx = ((size_t)b*Orows + o)*L + l;
          ((float*)outp)[idx] = res[idx] + a;
        } else {
          size_t idx = ((size_t)b*Orows + o)*L + l;
          ((float*)outp)[idx] += a;
        }
      }
    }
  }
}

// ---------------- depthwise 3x3, 8 px/thread, bf16, optional sum-of-squares ----------------
__global__ __launch_bounds__(256) void dwconv8_k(const ushort* __restrict__ in, const float* __restrict__ w9,
    ushort* __restrict__ out, float* __restrict__ ss, int Cc, int nss){
  int e  = blockIdx.x*256 + threadIdx.x;
  int bc = e >> 11;
  int p  = (e & 2047) * 8;
  int c  = bc % Cc, b = bc / Cc;
  int y  = p >> 7, x0 = p & 127;
  const ushort* ip = in + (size_t)bc*L;
  float w[9];
  #pragma unroll
  for (int i=0;i<9;++i) w[i] = w9[c*9+i];
  float v[3][10];
  #pragma unroll
  for (int r=0;r<3;++r){
    int yy = y + r - 1;
    if ((unsigned)yy >= IMG){
      #pragma unroll
      for (int j=0;j<10;++j) v[r][j]=0.f;
    } else {
      const ushort* rp = ip + yy*IMG + x0;
      uint4 cv = *(const uint4*)rp; const ushort* us = (const ushort*)&cv;
      #pragma unroll
      for (int j=0;j<8;++j) v[r][j+1] = u2f(us[j]);
      v[r][0] = (x0>0)   ? u2f(rp[-1]) : 0.f;
      v[r][9] = (x0<120) ? u2f(rp[8])  : 0.f;
    }
  }
  float sq = 0.f; ushort o8[8];
  #pragma unroll
  for (int j=0;j<8;++j){
    float a = 0.f;
    #pragma unroll
    for (int r=0;r<3;++r)
      #pragma unroll
      for (int dx=0;dx<3;++dx) a = fmaf(w[r*3+dx], v[r][j+dx], a);
    o8[j] = f2u(a); sq += a*a;
  }
  *(uint4*)(out + (size_t)bc*L + p) = *(const uint4*)o8;
  if (ss != nullptr && c < nss){
    #pragma unroll
    for (int off=32; off>0; off>>=1) sq += __shfl_xor(sq, off, 64);
    __shared__ float red[4];
    int wid = threadIdx.x >> 6;
    if ((threadIdx.x & 63)==0) red[wid]=sq;
    __syncthreads();
    if (threadIdx.x==0) atomicAdd(&ss[b*nss + c], red[0]+red[1]+red[2]+red[3]);
  }
}

// ---------------- QK^T via MFMA, k-split over L ----------------
__global__ __launch_bounds__(64) void qk_mfma_k(const ushort* __restrict__ qb, const ushort* __restrict__ kvb,
                                                float* __restrict__ P){
  int ks = blockIdx.x, bh = blockIdx.y;
  int b = bh >> 2, h = bh & 3;
  int lane = threadIdx.x, g16 = lane>>4, c16 = lane&15;
  const ushort* qbase = qb  + ((size_t)b*C0      + h*CHN)*L;
  const ushort* kbse  = kvb + ((size_t)b*(2*C0)  + h*CHN)*L;
  f32x4 acc[3][3];
  #pragma unroll
  for (int i=0;i<3;++i)
    #pragma unroll
    for (int j=0;j<3;++j){ f32x4 z={0.f,0.f,0.f,0.f}; acc[i][j]=z; }
  int k0 = ks * (L/KSPLIT);
  for (int kk=0; kk<(L/KSPLIT)/32; ++kk){
    int kb = k0 + kk*32;
    bf16x8 af[3], bv[3];
    #pragma unroll
    for (int i=0;i<3;++i){
      af[i] = ld_bf8(qbase + (size_t)(i*16+c16)*L + kb + g16*8);
      bv[i] = ld_bf8(kbse  + (size_t)(i*16+c16)*L + kb + g16*8);
    }
    #pragma unroll
    for (int mi=0;mi<3;++mi)
      #pragma unroll
      for (int ni=0;ni<3;++ni)
        acc[mi][ni] = mfma16(af[mi], bv[ni], acc[mi][ni]);
  }
  float* Pp = P + ((size_t)ks*(BATCH*NH) + bh)*CHN*CHN;
  #pragma unroll
  for (int mi=0;mi<3;++mi)
    #pragma unroll
    for (int ni=0;ni<3;++ni)
      #pragma unroll
      for (int r=0;r<4;++r){
        int m = mi*16 + g16*4 + r, n = ni*16 + c16;
        Pp[m*CHN + n] = acc[mi][ni][r];
      }
}

__global__ void reduceS_k(const float* __restrict__ P, float* __restrict__ S){
  int i = blockIdx.x*256 + threadIdx.x;
  if (i >= BATCH*NH*CHN*CHN) return;
  float s = 0.f;
  for (int ks=0; ks<KSPLIT; ++ks) s += P[(size_t)ks*(BATCH*NH*CHN*CHN) + i];
  S[i] = s;
}

// ---------------- softmax + gating + Wca modulation ----------------
__global__ void gating_k(const float* __restrict__ S, const float* __restrict__ qss,
                         const float* __restrict__ kss, const float* __restrict__ temp,
                         const float* __restrict__ Wca, float* __restrict__ attnF){
  int bh = blockIdx.x; int h = bh % NH; int b = bh / NH;
  int t = threadIdx.x;
  __shared__ float rk[CHN], rqv[CHN];
  if (t < CHN){
    float nk = sqrtf(kss[b*C0 + h*CHN + t]); rk[t]  = 1.f/fmaxf(nk, 1e-12f);
    float nq = sqrtf(qss[b*C0 + h*CHN + t]); rqv[t] = 1.f/fmaxf(nq, 1e-12f);
  }
  __syncthreads();
  if (t >= CHN) return;
  float T = temp[h];
  float rq = rqv[t];
  const float* Srow = S + ((size_t)bh*CHN + t)*CHN;
  float raw[CHN], a0[CHN], a1[CHN];
  float mx = -1e30f;
  for (int d=0;d<CHN;++d){ raw[d] = Srow[d]*rq*rk[d]*T; mx = fmaxf(mx, raw[d]); }
  float sum=0.f;
  for (int d=0;d<CHN;++d){ a0[d] = expf(raw[d]-mx); sum += a0[d]; }
  float inv = 1.f/sum;
  for (int d=0;d<CHN;++d){
    float r = fmaxf(raw[d],0.f); r = r*r;
    a1[d] = gelu_exact(r)*r;
  }
  float* outr = attnF + ((size_t)bh*CHN + t)*CHN;
  for (int d=0;d<CHN;++d){
    float s1=0.f, s2=0.f;
    const float* w1 = Wca + (size_t)d*CHN;
    const float* w2 = Wca + (size_t)(d+CHN)*CHN;
    for (int j=0;j<CHN;++j){ s1 = fmaf(w1[j], a1[j], s1); s2 = fmaf(w2[j], a1[j], s2); }
    outr[d] = a0[d]*inv*(1.f+s1) + s2;
  }
}

// Mtb[b][o][dfull] = sum_c Wproj[o][h*48+c] * attnF[b][h][c][d]   (bf16)
__global__ void mt_k(const float* __restrict__ Wproj, const float* __restrict__ attnF,
                     ushort* __restrict__ Mtb){
  int idx = blockIdx.x*256 + threadIdx.x;
  if (idx >= BATCH*C0*C0) return;
  int d = idx % C0; int o = (idx / C0) % C0; int b = idx / (C0*C0);
  int h = d / CHN, dd = d % CHN;
  float s=0.f;
  for (int c=0;c<CHN;++c)
    s = fmaf(Wproj[(size_t)o*C0 + h*CHN + c],
             attnF[(((size_t)(b*NH+h))*CHN + c)*CHN + dd], s);
  Mtb[idx] = f2u(s);
}

// ---------------- GDFN fused dwconv + gelu gate (writes 512 rows/b, pad rows zero) ----------------
__global__ __launch_bounds__(256) void ffn8_k(const ushort* __restrict__ hidden, const float* __restrict__ w9,
                                              ushort* __restrict__ g){
  int e  = blockIdx.x*256 + threadIdx.x;
  int bg = e >> 11;
  int p  = (e & 2047) * 8;
  int go = bg & 511, b = bg >> 9;
  ushort* op = g + (size_t)bg*L + p;
  if (go >= HID){ uint4 z = {0,0,0,0}; *(uint4*)op = z; return; }
  int y = p >> 7, x0 = p & 127;
  const ushort* i1 = hidden + ((size_t)b*HID2 + go)*L;
  const ushort* i2 = i1 + (size_t)HID*L;
  float w1[9], w2[9];
  #pragma unroll
  for (int i=0;i<9;++i){ w1[i] = w9[go*9+i]; w2[i] = w9[(HID+go)*9+i]; }
  float v1[3][10], v2[3][10];
  #pragma unroll
  for (int r=0;r<3;++r){
    int yy = y + r - 1;
    if ((unsigned)yy >= IMG){
      #pragma unroll
      for (int j=0;j<10;++j){ v1[r][j]=0.f; v2[r][j]=0.f; }
    } else {
      const ushort* rp1 = i1 + yy*IMG + x0;
      const ushort* rp2 = i2 + yy*IMG + x0;
      uint4 c1 = *(const uint4*)rp1; const ushort* u1 = (const ushort*)&c1;
      uint4 c2 = *(const uint4*)rp2; const ushort* u2 = (const ushort*)&c2;
      #pragma unroll
      for (int j=0;j<8;++j){ v1[r][j+1] = u2f(u1[j]); v2[r][j+1] = u2f(u2[j]); }
      v1[r][0] = (x0>0)   ? u2f(rp1[-1]) : 0.f;
      v1[r][9] = (x0<120) ? u2f(rp1[8])  : 0.f;
      v2[r][0] = (x0>0)   ? u2f(rp2[-1]) : 0.f;
      v2[r][9] = (x0<120) ? u2f(rp2[8])  : 0.f;
    }
  }
  ushort o8[8];
  #pragma unroll
  for (int j=0;j<8;++j){
    float d1=0.f, d2=0.f;
    #pragma unroll
    for (int r=0;r<3;++r)
      #pragma unroll
      for (int dx=0;dx<3;++dx){
        d1 = fmaf(w1[r*3+dx], v1[r][j+dx], d1);
        d2 = fmaf(w2[r*3+dx], v2[r][j+dx], d2);
      }
    o8[j] = f2u(gelu_exact(d1)*d2);
  }
  *(uint4*)op = *(const uint4*)o8;
}

extern "C" void kernel_launch(void* const* d_in, const int* in_sizes, int n_in,
                              void* d_out, int out_size, void* d_ws, size_t ws_size,
                              hipStream_t stream){
  (void)in_sizes; (void)n_in; (void)out_size; (void)ws_size;
  const float* lr    = (const float*)d_in[0];
  const float* ref   = (const float*)d_in[1];
  const float* ln1w  = (const float*)d_in[2];
  const float* ln1b  = (const float*)d_in[3];
  const float* lnrw  = (const float*)d_in[4];
  const float* lnrb  = (const float*)d_in[5];
  const float* ln2w  = (const float*)d_in[6];
  const float* ln2b  = (const float*)d_in[7];
  const float* Wq    = (const float*)d_in[8];
  const float* qdw   = (const float*)d_in[9];
  const float* Wkv   = (const float*)d_in[10];
  const float* kvdw  = (const float*)d_in[11];
  const float* Wproj = (const float*)d_in[12];
  const float* Wca   = (const float*)d_in[13];
  const float* temp  = (const float*)d_in[14];
  const float* Wpin  = (const float*)d_in[15];
  const float* ffndw = (const float*)d_in[16];
  const float* Wpout = (const float*)d_in[17];
  float* out = (float*)d_out;

  char* ws = (char*)d_ws;
  size_t off = 0;
  auto alloc = [&](size_t bytes)->void*{ void* p = ws + off; off += (bytes + 255) & ~(size_t)255; return p; };

  ushort* Aqbf   = (ushort*)alloc((size_t)192*192*2);
  ushort* Akvbf  = (ushort*)alloc((size_t)384*192*2);
  ushort* Apinbf = (ushort*)alloc((size_t)1024*192*2);
  ushort* Apoutbf= (ushort*)alloc((size_t)192*512*2);
  ushort* Mtb    = (ushort*)alloc((size_t)BATCH*C0*C0*2);
  float* Aqv  = (float*)alloc(192*4);   float* Bqv  = (float*)alloc(192*4);
  float* Akvv = (float*)alloc(384*4);   float* Bkvv = (float*)alloc(384*4);
  float* Apinv= (float*)alloc(1024*4);  float* Bpinv= (float*)alloc(1024*4);
  float* mu_lr = (float*)alloc((size_t)BL*4);  float* rs_lr = (float*)alloc((size_t)BL*4);
  float* mu_rf = (float*)alloc((size_t)BL*4);  float* rs_rf = (float*)alloc((size_t)BL*4);
  float* mu_o  = (float*)alloc((size_t)BL*4);  float* rs_o  = (float*)alloc((size_t)BL*4);
  float* qss   = (float*)alloc((size_t)BATCH*C0*4);
  float* kss   = (float*)alloc((size_t)BATCH*C0*4);
  float* S     = (float*)alloc((size_t)BATCH*NH*CHN*CHN*4);
  float* attnF = (float*)alloc((size_t)BATCH*NH*CHN*CHN*4);
  char*  pool  = (char*)alloc((size_t)109051904);

  ushort* q_pre  = (ushort*)(pool);                       // 12,582,912
  ushort* kv_pre = (ushort*)(pool + 12582912);            // 25,165,824
  ushort* qb     = (ushort*)(pool + 37748736);            // 12,582,912
  ushort* kvb    = (ushort*)(pool + 50331648);            // 25,165,824
  float*  Pp     = (float*) (pool);                       // 9,437,184 (overlays q_pre, dead then)
  ushort* hidden = (ushort*)(pool);                       // 66,846,720 (overlays first 4, dead then)
  ushort* g      = (ushort*)(pool + 75497472);            // 33,554,432

  hipMemsetAsync(qss, 0, (size_t)BATCH*C0*4, stream);
  hipMemsetAsync(kss, 0, (size_t)BATCH*C0*4, stream);

  // weight prep
  packw_k<<<(192*192+255)/256,256,0,stream>>>(Wq,   ln1w, Aqbf,   192, 192, 192, 192*192);
  packw_k<<<(384*192+255)/256,256,0,stream>>>(Wkv,  lnrw, Akvbf,  192, 384, 192, 384*192);
  packw_k<<<(1024*192+255)/256,256,0,stream>>>(Wpin, ln2w, Apinbf, 192, 1020, 192, 1024*192);
  packw_k<<<(192*512+255)/256,256,0,stream>>>(Wpout, nullptr, Apoutbf, 510, 192, 512, 192*512);
  prepab_k<<<1,256,0,stream>>>(Wq,  ln1w, ln1b, Aqv,  Bqv,  192, 192, 192);
  prepab_k<<<2,256,0,stream>>>(Wkv, lnrw, lnrb, Akvv, Bkvv, 192, 384, 384);
  prepab_k<<<4,256,0,stream>>>(Wpin,ln2w, ln2b, Apinv,Bpinv,192, 1020, 1024);

  // LN stats
  ln_stats_k<<<BL/256,256,0,stream>>>(lr,  mu_lr, rs_lr);
  ln_stats_k<<<BL/256,256,0,stream>>>(ref, mu_rf, rs_rf);

  // fused LN + 1x1 conv GEMMs (MFMA)
  gemm_k<0,true><<<dim3(256,3),256,0,stream>>>(Aqbf, 192, 0, lr, (size_t)C0*L,
      mu_lr, rs_lr, Aqv, Bqv, nullptr, q_pre, 192, 192);
  gemm_k<0,true><<<dim3(256,6),256,0,stream>>>(Akvbf, 192, 0, ref, (size_t)C0*L,
      mu_rf, rs_rf, Akvv, Bkvv, nullptr, kv_pre, 384, 384);

  // depthwise convs + l2 sum-of-squares
  dwconv8_k<<<(BATCH*192*L/8)/256,256,0,stream>>>(q_pre,  qdw,  qb,  qss, 192, 192);
  dwconv8_k<<<(BATCH*384*L/8)/256,256,0,stream>>>(kv_pre, kvdw, kvb, kss, 384, 192);

  // attention core
  qk_mfma_k<<<dim3(KSPLIT, BATCH*NH),64,0,stream>>>(qb, kvb, Pp);
  reduceS_k<<<(BATCH*NH*CHN*CHN+255)/256,256,0,stream>>>(Pp, S);
  gating_k<<<BATCH*NH,64,0,stream>>>(S, qss, kss, temp, Wca, attnF);
  mt_k<<<(BATCH*C0*C0+255)/256,256,0,stream>>>(Wproj, attnF, Mtb);

  // out = lr + Mt . v
  gemm_k<1,false><<<dim3(256,3),256,0,stream>>>(Mtb, 192, 192*192, kvb + (size_t)C0*L, (size_t)2*C0*L,
      nullptr, nullptr, nullptr, nullptr, lr, out, 192, 192);

  // GDFN
  ln_stats_k<<<BL/256,256,0,stream>>>(out, mu_o, rs_o);
  gemm_k<0,true><<<dim3(256,16),256,0,stream>>>(Apinbf, 192, 0, out, (size_t)C0*L,
      mu_o, rs_o, Apinv, Bpinv, nullptr, hidden, 1020, 1020);
  ffn8_k<<<(BATCH*512*L/8)/256,256,0,stream>>>(hidden, ffndw, g);
  gemm_k<2,false><<<dim3(256,3),256,0,stream>>>(Apoutbf, 512, 0, g, (size_t)512*L,
      nullptr, nullptr, nullptr, nullptr, nullptr, out, 192, 192);
}

// Round 3
// 475.097 us; speedup vs baseline: 2.9800x; 1.1319x over previous
//
#include <hip/hip_runtime.h>
#include <hip/hip_bf16.h>
#include <math.h>

#define L     16384
#define IMG   128
#define BATCH 2
#define C0    192
#define NH    4
#define CHN   48
#define HID   510
#define HID2  1020
#define BL    (BATCH*L)
#define KSPLIT 128

typedef float  f32x4  __attribute__((ext_vector_type(4)));
typedef __bf16 bf16x8 __attribute__((ext_vector_type(8)));

union UB16 { uint4 u; bf16x8 v; };

__device__ __forceinline__ bf16x8 ld_bf8(const ushort* p){ UB16 x; x.u = *(const uint4*)p; return x.v; }
__device__ __forceinline__ f32x4 mfma16(bf16x8 a, bf16x8 b, f32x4 c){
  return __builtin_amdgcn_mfma_f32_16x16x32_bf16(a, b, c, 0, 0, 0);
}
__device__ __forceinline__ float u2f(ushort u){ union{unsigned u; float f;} x; x.u = ((unsigned)u)<<16; return x.f; }
__device__ __forceinline__ ushort f2u(float f){ __hip_bfloat16 h = __float2bfloat16(f); return *reinterpret_cast<ushort*>(&h); }
__device__ __forceinline__ float gelu_exact(float x){ return 0.5f*x*(1.0f+erff(x*0.70710678118654752f)); }

// ---------------- per-position channel-LN stats ----------------
__global__ __launch_bounds__(256) void ln_stats_k(const float* __restrict__ x,
                                                  float* __restrict__ mu, float* __restrict__ rsig){
  int pos = blockIdx.x*256 + threadIdx.x;
  int b = pos >> 14, l = pos & (L-1);
  const float* xp = x + (size_t)b*C0*L + l;
  float s=0.f, ss=0.f;
  for (int c=0;c<C0;++c){ float v = xp[(size_t)c*L]; s += v; ss += v*v; }
  float m = s*(1.f/C0);
  float var = ss*(1.f/C0) - m*m;
  mu[pos]=m; rsig[pos]=rsqrtf(var + 1e-5f);
}

// ---------------- weight packing (fp32 -> bf16, [Mpad][Kpad] row-major) ----------------
__global__ void packw_k(const float* __restrict__ W, const float* __restrict__ lnw,
                        ushort* __restrict__ out, int Csrc, int O, int Kpad, int total){
  int idx = blockIdx.x*256 + threadIdx.x;
  if (idx >= total) return;
  int m = idx / Kpad, k = idx - m*Kpad;
  float v = 0.f;
  if (k < Csrc && m < O){ v = W[(size_t)m*Csrc + k]; if (lnw) v *= lnw[k]; }
  out[idx] = f2u(v);
}

// A[o]=sum_c W[o,c]*lnw[c]; B[o]=sum_c W[o,c]*lnb[c]  (padded to Opad)
__global__ void prepab_k(const float* __restrict__ W, const float* __restrict__ lnw,
                         const float* __restrict__ lnb, float* __restrict__ A, float* __restrict__ Bv,
                         int Cc, int O, int Opad){
  int o = blockIdx.x*256 + threadIdx.x;
  if (o >= Opad) return;
  float a=0.f,b=0.f;
  if (o < O){
    const float* wr = W + (size_t)o*Cc;
    for (int c=0;c<Cc;++c){ float w=wr[c]; a = fmaf(w, lnw[c], a); b = fmaf(w, lnb[c], b); }
  }
  A[o]=a; Bv[o]=b;
}

// ---------------- MFMA GEMM: OUT[o,pos] = epilogue( sum_k A[o,k]*X[k,pos] ) ----------------
// A: bf16 [Mpad][Kpad] row-major. X: [b][rows][L] (bf16 or f32). Tile: M64 x N128, 4 waves.
// EPI 0: LN  -> bf16 out = rs*(acc - mu*Avec[o]) + Bvec[o]
// EPI 1: RES -> f32 out = res + acc
// EPI 2: ADD -> f32 out += acc
template<int EPI, bool BF32>
__global__ __launch_bounds__(256) void gemm_k(
    const ushort* __restrict__ A, int Kpad, int aBatchStride,
    const void* __restrict__ X, size_t xBS,
    const float* __restrict__ mu, const float* __restrict__ rs,
    const float* __restrict__ Avec, const float* __restrict__ Bvec,
    const float* __restrict__ res,
    void* __restrict__ outp, int Orows, int Ovalid)
{
  __shared__ ushort xt[128][40];
  const int tid  = threadIdx.x;
  const int lane = tid & 63, w = tid >> 6;
  const int nblk = blockIdx.x;
  const int b    = nblk >> 7;
  const int l0   = (nblk & 127) * 128;
  const int mbase= blockIdx.y * 64;
  const int g16  = lane >> 4, c16 = lane & 15;

  const ushort* Ab = A + (size_t)b * aBatchStride;

  f32x4 acc[4][2];
  #pragma unroll
  for (int mi=0; mi<4; ++mi)
    #pragma unroll
    for (int ni=0; ni<2; ++ni){ f32x4 z = {0.f,0.f,0.f,0.f}; acc[mi][ni] = z; }

  const int sc2  = (tid & 15) * 2;
  const int spos = (tid >> 4) * 8;
  const int kSteps = Kpad >> 5;

  for (int ks = 0; ks < kSteps; ++ks){
    const int kbase = ks << 5;
    // ---- load staging data (2 rows x 8 pos) + A fragments (global, L2) ----
    ushort ua[8], ub[8];
    if (BF32){
      const float* xr = (const float*)X + (size_t)b*xBS + (size_t)(kbase+sc2)*L + l0 + spos;
      float fa[8], fb[8];
      *(float4*)&fa[0] = *(const float4*)xr;       *(float4*)&fa[4] = *(const float4*)(xr+4);
      *(float4*)&fb[0] = *(const float4*)(xr+L);   *(float4*)&fb[4] = *(const float4*)(xr+L+4);
      #pragma unroll
      for (int j=0;j<8;++j){ ua[j]=f2u(fa[j]); ub[j]=f2u(fb[j]); }
    } else {
      const ushort* xr = (const ushort*)X + (size_t)b*xBS + (size_t)(kbase+sc2)*L + l0 + spos;
      uint4 ra = *(const uint4*)xr; uint4 rb = *(const uint4*)(xr+L);
      const ushort* pa = (const ushort*)&ra; const ushort* pb = (const ushort*)&rb;
      #pragma unroll
      for (int j=0;j<8;++j){ ua[j]=pa[j]; ub[j]=pb[j]; }
    }
    bf16x8 af[4];
    #pragma unroll
    for (int mi=0; mi<4; ++mi)
      af[mi] = ld_bf8(Ab + (size_t)(mbase + mi*16 + c16)*Kpad + kbase + g16*8);

    __syncthreads();
    #pragma unroll
    for (int j=0;j<8;++j){ ushort2 t2; t2.x = ua[j]; t2.y = ub[j]; *(ushort2*)&xt[spos+j][sc2] = t2; }
    __syncthreads();

    bf16x8 bv[2];
    #pragma unroll
    for (int ni=0; ni<2; ++ni)
      bv[ni] = ld_bf8(&xt[w*32 + ni*16 + c16][g16*8]);
    #pragma unroll
    for (int mi=0; mi<4; ++mi)
      #pragma unroll
      for (int ni=0; ni<2; ++ni)
        acc[mi][ni] = mfma16(af[mi], bv[ni], acc[mi][ni]);
  }

  // ---- epilogue ----
  const int rowOff = g16*4;
  #pragma unroll
  for (int ni=0; ni<2; ++ni){
    int nl = w*32 + ni*16 + c16;
    int l  = l0 + nl;
    float muv=0.f, rsv=0.f;
    if (EPI == 0){ int pos = b*L + l; muv = mu[pos]; rsv = rs[pos]; }
    #pragma unroll
    for (int mi=0; mi<4; ++mi){
      #pragma unroll
      for (int r=0; r<4; ++r){
        int o = mbase + mi*16 + rowOff + r;
        float a = acc[mi][ni][r];
        if (EPI == 0){
          if (o < Ovalid){
            float vv = rsv*(a - muv*Avec[o]) + Bvec[o];
            ((ushort*)outp)[((size_t)b*Orows + o)*L + l] = f2u(vv);
          }
        } else if (EPI == 1){
          size_t idx = ((size_t)b*Orows + o)*L + l;
          ((float*)outp)[idx] = res[idx] + a;
        } else {
          size_t idx = ((size_t)b*Orows + o)*L + l;
          ((float*)outp)[idx] += a;
        }
      }
    }
  }
}

// ---------------- depthwise 3x3, 8 px/thread, bf16, optional sum-of-squares ----------------
__global__ __launch_bounds__(256) void dwconv8_k(const ushort* __restrict__ in, const float* __restrict__ w9,
    ushort* __restrict__ out, float* __restrict__ ss, int Cc, int nss){
  int e  = blockIdx.x*256 + threadIdx.x;
  int bc = e >> 11;
  int p  = (e & 2047) * 8;
  int c  = bc % Cc, b = bc / Cc;
  int y  = p >> 7, x0 = p & 127;
  const ushort* ip = in + (size_t)bc*L;
  float w[9];
  #pragma unroll
  for (int i=0;i<9;++i) w[i] = w9[c*9+i];
  float v[3][10];
  #pragma unroll
  for (int r=0;r<3;++r){
    int yy = y + r - 1;
    if ((unsigned)yy >= IMG){
      #pragma unroll
      for (int j=0;j<10;++j) v[r][j]=0.f;
    } else {
      const ushort* rp = ip + yy*IMG + x0;
      uint4 cv = *(const uint4*)rp; const ushort* us = (const ushort*)&cv;
      #pragma unroll
      for (int j=0;j<8;++j) v[r][j+1] = u2f(us[j]);
      v[r][0] = (x0>0)   ? u2f(rp[-1]) : 0.f;
      v[r][9] = (x0<120) ? u2f(rp[8])  : 0.f;
    }
  }
  float sq = 0.f; ushort o8[8];
  #pragma unroll
  for (int j=0;j<8;++j){
    float a = 0.f;
    #pragma unroll
    for (int r=0;r<3;++r)
      #pragma unroll
      for (int dx=0;dx<3;++dx) a = fmaf(w[r*3+dx], v[r][j+dx], a);
    o8[j] = f2u(a); sq += a*a;
  }
  *(uint4*)(out + (size_t)bc*L + p) = *(const uint4*)o8;
  if (ss != nullptr && c < nss){
    #pragma unroll
    for (int off=32; off>0; off>>=1) sq += __shfl_xor(sq, off, 64);
    __shared__ float red[4];
    int wid = threadIdx.x >> 6;
    if ((threadIdx.x & 63)==0) red[wid]=sq;
    __syncthreads();
    if (threadIdx.x==0) atomicAdd(&ss[b*nss + c], red[0]+red[1]+red[2]+red[3]);
  }
}

// ---------------- QK^T via MFMA, k-split over L ----------------
__global__ __launch_bounds__(64) void qk_mfma_k(const ushort* __restrict__ qb, const ushort* __restrict__ kvb,
                                                float* __restrict__ P){
  int ks = blockIdx.x, bh = blockIdx.y;
  int b = bh >> 2, h = bh & 3;
  int lane = threadIdx.x, g16 = lane>>4, c16 = lane&15;
  const ushort* qbase = qb  + ((size_t)b*C0      + h*CHN)*L;
  const ushort* kbse  = kvb + ((size_t)b*(2*C0)  + h*CHN)*L;
  f32x4 acc[3][3];
  #pragma unroll
  for (int i=0;i<3;++i)
    #pragma unroll
    for (int j=0;j<3;++j){ f32x4 z={0.f,0.f,0.f,0.f}; acc[i][j]=z; }
  int k0 = ks * (L/KSPLIT);
  for (int kk=0; kk<(L/KSPLIT)/32; ++kk){
    int kb = k0 + kk*32;
    bf16x8 af[3], bv[3];
    #pragma unroll
    for (int i=0;i<3;++i){
      af[i] = ld_bf8(qbase + (size_t)(i*16+c16)*L + kb + g16*8);
      bv[i] = ld_bf8(kbse  + (size_t)(i*16+c16)*L + kb + g16*8);
    }
    #pragma unroll
    for (int mi=0;mi<3;++mi)
      #pragma unroll
      for (int ni=0;ni<3;++ni)
        acc[mi][ni] = mfma16(af[mi], bv[ni], acc[mi][ni]);
  }
  float* Pp = P + ((size_t)ks*(BATCH*NH) + bh)*CHN*CHN;
  #pragma unroll
  for (int mi=0;mi<3;++mi)
    #pragma unroll
    for (int ni=0;ni<3;++ni)
      #pragma unroll
      for (int r=0;r<4;++r){
        int m = mi*16 + g16*4 + r, n = ni*16 + c16;
        Pp[m*CHN + n] = acc[mi][ni][r];
      }
}

__global__ void reduceS_k(const float* __restrict__ P, float* __restrict__ S){
  int i = blockIdx.x*256 + threadIdx.x;
  if (i >= BATCH*NH*CHN*CHN) return;
  float s = 0.f;
  for (int ks=0; ks<KSPLIT; ++ks) s += P[(size_t)ks*(BATCH*NH*CHN*CHN) + i];
  S[i] = s;
}

// ---------------- softmax + gating + Wca modulation: one wave per (b,h,c) row ----------------
__global__ __launch_bounds__(64) void gating_k(const float* __restrict__ S, const float* __restrict__ qss,
                         const float* __restrict__ kss, const float* __restrict__ temp,
                         const float* __restrict__ Wca, float* __restrict__ attnF){
  int blk = blockIdx.x;                 // bh*CHN + c
  int c  = blk % CHN; int bh = blk / CHN;
  int h  = bh & 3, b = bh >> 2;
  int d  = threadIdx.x;                 // lane; active for d < 48
  bool act = (d < CHN);

  float T  = temp[h];
  float nq = sqrtf(qss[b*C0 + h*CHN + c]);
  float rq = 1.f/fmaxf(nq, 1e-12f);
  float rk = 0.f, sv = 0.f;
  if (act){
    float nk = sqrtf(kss[b*C0 + h*CHN + d]);
    rk = 1.f/fmaxf(nk, 1e-12f);
    sv = S[((size_t)bh*CHN + c)*CHN + d];
  }
  float raw = act ? sv*rq*rk*T : -1e30f;

  // softmax across 48 active lanes
  float mx = raw;
  #pragma unroll
  for (int off=32; off>0; off>>=1) mx = fmaxf(mx, __shfl_xor(mx, off, 64));
  float e = act ? expf(raw - mx) : 0.f;
  float sum = e;
  #pragma unroll
  for (int off=32; off>0; off>>=1) sum += __shfl_xor(sum, off, 64);
  float a0 = e / sum;

  // a1 = gelu(relu(raw)^2) * relu(raw)^2, broadcast via LDS
  float r = fmaxf(raw, 0.f); r = r*r;
  float a1 = gelu_exact(r)*r;
  __shared__ float a1s[CHN];
  if (act) a1s[d] = a1;
  __syncthreads();

  if (!act) return;
  float s1 = 0.f, s2 = 0.f;
  const float* w1 = Wca + (size_t)d*CHN;
  const float* w2 = Wca + (size_t)(d+CHN)*CHN;
  #pragma unroll
  for (int j=0;j<CHN;++j){
    float aj = a1s[j];
    s1 = fmaf(w1[j], aj, s1);
    s2 = fmaf(w2[j], aj, s2);
  }
  attnF[((size_t)bh*CHN + c)*CHN + d] = a0*(1.f+s1) + s2;
}

// Mtb[b][o][dfull] = sum_c Wproj[o][h*48+c] * attnF[b][h][c][d]   (bf16)
__global__ void mt_k(const float* __restrict__ Wproj, const float* __restrict__ attnF,
                     ushort* __restrict__ Mtb){
  int idx = blockIdx.x*256 + threadIdx.x;
  if (idx >= BATCH*C0*C0) return;
  int d = idx % C0; int o = (idx / C0) % C0; int b = idx / (C0*C0);
  int h = d / CHN, dd = d % CHN;
  float s=0.f;
  for (int c=0;c<CHN;++c)
    s = fmaf(Wproj[(size_t)o*C0 + h*CHN + c],
             attnF[(((size_t)(b*NH+h))*CHN + c)*CHN + dd], s);
  Mtb[idx] = f2u(s);
}

// ---------------- GDFN fused dwconv + gelu gate (writes 512 rows/b, pad rows zero) ----------------
__global__ __launch_bounds__(256) void ffn8_k(const ushort* __restrict__ hidden, const float* __restrict__ w9,
                                              ushort* __restrict__ g){
  int e  = blockIdx.x*256 + threadIdx.x;
  int bg = e >> 11;
  int p  = (e & 2047) * 8;
  int go = bg & 511, b = bg >> 9;
  ushort* op = g + (size_t)bg*L + p;
  if (go >= HID){ uint4 z = {0,0,0,0}; *(uint4*)op = z; return; }
  int y = p >> 7, x0 = p & 127;
  const ushort* i1 = hidden + ((size_t)b*HID2 + go)*L;
  const ushort* i2 = i1 + (size_t)HID*L;
  float w1[9], w2[9];
  #pragma unroll
  for (int i=0;i<9;++i){ w1[i] = w9[go*9+i]; w2[i] = w9[(HID+go)*9+i]; }
  float v1[3][10], v2[3][10];
  #pragma unroll
  for (int r=0;r<3;++r){
    int yy = y + r - 1;
    if ((unsigned)yy >= IMG){
      #pragma unroll
      for (int j=0;j<10;++j){ v1[r][j]=0.f; v2[r][j]=0.f; }
    } else {
      const ushort* rp1 = i1 + yy*IMG + x0;
      const ushort* rp2 = i2 + yy*IMG + x0;
      uint4 c1 = *(const uint4*)rp1; const ushort* u1 = (const ushort*)&c1;
      uint4 c2 = *(const uint4*)rp2; const ushort* u2 = (const ushort*)&c2;
      #pragma unroll
      for (int j=0;j<8;++j){ v1[r][j+1] = u2f(u1[j]); v2[r][j+1] = u2f(u2[j]); }
      v1[r][0] = (x0>0)   ? u2f(rp1[-1]) : 0.f;
      v1[r][9] = (x0<120) ? u2f(rp1[8])  : 0.f;
      v2[r][0] = (x0>0)   ? u2f(rp2[-1]) : 0.f;
      v2[r][9] = (x0<120) ? u2f(rp2[8])  : 0.f;
    }
  }
  ushort o8[8];
  #pragma unroll
  for (int j=0;j<8;++j){
    float d1=0.f, d2=0.f;
    #pragma unroll
    for (int r=0;r<3;++r)
      #pragma unroll
      for (int dx=0;dx<3;++dx){
        d1 = fmaf(w1[r*3+dx], v1[r][j+dx], d1);
        d2 = fmaf(w2[r*3+dx], v2[r][j+dx], d2);
      }
    o8[j] = f2u(gelu_exact(d1)*d2);
  }
  *(uint4*)op = *(const uint4*)o8;
}

extern "C" void kernel_launch(void* const* d_in, const int* in_sizes, int n_in,
                              void* d_out, int out_size, void* d_ws, size_t ws_size,
                              hipStream_t stream){
  (void)in_sizes; (void)n_in; (void)out_size; (void)ws_size;
  const float* lr    = (const float*)d_in[0];
  const float* ref   = (const float*)d_in[1];
  const float* ln1w  = (const float*)d_in[2];
  const float* ln1b  = (const float*)d_in[3];
  const float* lnrw  = (const float*)d_in[4];
  const float* lnrb  = (const float*)d_in[5];
  const float* ln2w  = (const float*)d_in[6];
  const float* ln2b  = (const float*)d_in[7];
  const float* Wq    = (const float*)d_in[8];
  const float* qdw   = (const float*)d_in[9];
  const float* Wkv   = (const float*)d_in[10];
  const float* kvdw  = (const float*)d_in[11];
  const float* Wproj = (const float*)d_in[12];
  const float* Wca   = (const float*)d_in[13];
  const float* temp  = (const float*)d_in[14];
  const float* Wpin  = (const float*)d_in[15];
  const float* ffndw = (const float*)d_in[16];
  const float* Wpout = (const float*)d_in[17];
  float* out = (float*)d_out;

  char* ws = (char*)d_ws;
  size_t off = 0;
  auto alloc = [&](size_t bytes)->void*{ void* p = ws + off; off += (bytes + 255) & ~(size_t)255; return p; };

  ushort* Aqbf   = (ushort*)alloc((size_t)192*192*2);
  ushort* Akvbf  = (ushort*)alloc((size_t)384*192*2);
  ushort* Apinbf = (ushort*)alloc((size_t)1024*192*2);
  ushort* Apoutbf= (ushort*)alloc((size_t)192*512*2);
  ushort* Mtb    = (ushort*)alloc((size_t)BATCH*C0*C0*2);
  float* Aqv  = (float*)alloc(192*4);   float* Bqv  = (float*)alloc(192*4);
  float* Akvv = (float*)alloc(384*4);   float* Bkvv = (float*)alloc(384*4);
  float* Apinv= (float*)alloc(1024*4);  float* Bpinv= (float*)alloc(1024*4);
  float* mu_lr = (float*)alloc((size_t)BL*4);  float* rs_lr = (float*)alloc((size_t)BL*4);
  float* mu_rf = (float*)alloc((size_t)BL*4);  float* rs_rf = (float*)alloc((size_t)BL*4);
  float* mu_o  = (float*)alloc((size_t)BL*4);  float* rs_o  = (float*)alloc((size_t)BL*4);
  float* qss   = (float*)alloc((size_t)BATCH*C0*4);
  float* kss   = (float*)alloc((size_t)BATCH*C0*4);
  float* S     = (float*)alloc((size_t)BATCH*NH*CHN*CHN*4);
  float* attnF = (float*)alloc((size_t)BATCH*NH*CHN*CHN*4);
  char*  pool  = (char*)alloc((size_t)109051904);

  ushort* q_pre  = (ushort*)(pool);                       // 12,582,912
  ushort* kv_pre = (ushort*)(pool + 12582912);            // 25,165,824
  ushort* qb     = (ushort*)(pool + 37748736);            // 12,582,912
  ushort* kvb    = (ushort*)(pool + 50331648);            // 25,165,824
  float*  Pp     = (float*) (pool);                       // 9,437,184 (overlays q_pre, dead then)
  ushort* hidden = (ushort*)(pool);                       // 66,846,720 (overlays first 4, dead then)
  ushort* g      = (ushort*)(pool + 75497472);            // 33,554,432

  hipMemsetAsync(qss, 0, (size_t)BATCH*C0*4, stream);
  hipMemsetAsync(kss, 0, (size_t)BATCH*C0*4, stream);

  // weight prep
  packw_k<<<(192*192+255)/256,256,0,stream>>>(Wq,   ln1w, Aqbf,   192, 192, 192, 192*192);
  packw_k<<<(384*192+255)/256,256,0,stream>>>(Wkv,  lnrw, Akvbf,  192, 384, 192, 384*192);
  packw_k<<<(1024*192+255)/256,256,0,stream>>>(Wpin, ln2w, Apinbf, 192, 1020, 192, 1024*192);
  packw_k<<<(192*512+255)/256,256,0,stream>>>(Wpout, nullptr, Apoutbf, 510, 192, 512, 192*512);
  prepab_k<<<1,256,0,stream>>>(Wq,  ln1w, ln1b, Aqv,  Bqv,  192, 192, 192);
  prepab_k<<<2,256,0,stream>>>(Wkv, lnrw, lnrb, Akvv, Bkvv, 192, 384, 384);
  prepab_k<<<4,256,0,stream>>>(Wpin,ln2w, ln2b, Apinv,Bpinv,192, 1020, 1024);

  // LN stats
  ln_stats_k<<<BL/256,256,0,stream>>>(lr,  mu_lr, rs_lr);
  ln_stats_k<<<BL/256,256,0,stream>>>(ref, mu_rf, rs_rf);

  // fused LN + 1x1 conv GEMMs (MFMA)
  gemm_k<0,true><<<dim3(256,3),256,0,stream>>>(Aqbf, 192, 0, lr, (size_t)C0*L,
      mu_lr, rs_lr, Aqv, Bqv, nullptr, q_pre, 192, 192);
  gemm_k<0,true><<<dim3(256,6),256,0,stream>>>(Akvbf, 192, 0, ref, (size_t)C0*L,
      mu_rf, rs_rf, Akvv, Bkvv, nullptr, kv_pre, 384, 384);

  // depthwise convs + l2 sum-of-squares
  dwconv8_k<<<(BATCH*192*L/8)/256,256,0,stream>>>(q_pre,  qdw,  qb,  qss, 192, 192);
  dwconv8_k<<<(BATCH*384*L/8)/256,256,0,stream>>>(kv_pre, kvdw, kvb, kss, 384, 192);

  // attention core
  qk_mfma_k<<<dim3(KSPLIT, BATCH*NH),64,0,stream>>>(qb, kvb, Pp);
  reduceS_k<<<(BATCH*NH*CHN*CHN+255)/256,256,0,stream>>>(Pp, S);
  gating_k<<<BATCH*NH*CHN,64,0,stream>>>(S, qss, kss, temp, Wca, attnF);
  mt_k<<<(BATCH*C0*C0+255)/256,256,0,stream>>>(Wproj, attnF, Mtb);

  // out = lr + Mt . v
  gemm_k<1,false><<<dim3(256,3),256,0,stream>>>(Mtb, 192, 192*192, kvb + (size_t)C0*L, (size_t)2*C0*L,
      nullptr, nullptr, nullptr, nullptr, lr, out, 192, 192);

  // GDFN
  ln_stats_k<<<BL/256,256,0,stream>>>(out, mu_o, rs_o);
  gemm_k<0,true><<<dim3(256,16),256,0,stream>>>(Apinbf, 192, 0, out, (size_t)C0*L,
      mu_o, rs_o, Apinv, Bpinv, nullptr, hidden, 1020, 1020);
  ffn8_k<<<(BATCH*512*L/8)/256,256,0,stream>>>(hidden, ffndw, g);
  gemm_k<2,false><<<dim3(256,3),256,0,stream>>>(Apoutbf, 512, 0, g, (size_t)512*L,
      nullptr, nullptr, nullptr, nullptr, nullptr, out, 192, 192);
}

// Round 4
// 459.003 us; speedup vs baseline: 3.0845x; 1.0351x over previous
//
#include <hip/hip_runtime.h>
#include <hip/hip_bf16.h>
#include <math.h>

#define L     16384
#define IMG   128
#define BATCH 2
#define C0    192
#define NH    4
#define CHN   48
#define HID   510
#define HID2  1020
#define BL    (BATCH*L)
#define KSPLIT 128

typedef float  f32x4  __attribute__((ext_vector_type(4)));
typedef __bf16 bf16x8 __attribute__((ext_vector_type(8)));

union UB16 { uint4 u; bf16x8 v; };

__device__ __forceinline__ bf16x8 ld_bf8(const ushort* p){ UB16 x; x.u = *(const uint4*)p; return x.v; }
__device__ __forceinline__ f32x4 mfma16(bf16x8 a, bf16x8 b, f32x4 c){
  return __builtin_amdgcn_mfma_f32_16x16x32_bf16(a, b, c, 0, 0, 0);
}
__device__ __forceinline__ float u2f(ushort u){ union{unsigned u; float f;} x; x.u = ((unsigned)u)<<16; return x.f; }
__device__ __forceinline__ ushort f2u(float f){ __hip_bfloat16 h = __float2bfloat16(f); return *reinterpret_cast<ushort*>(&h); }
__device__ __forceinline__ float gelu_exact(float x){ return 0.5f*x*(1.0f+erff(x*0.70710678118654752f)); }

// ---------------- per-position channel-LN stats ----------------
__global__ __launch_bounds__(256) void ln_stats_k(const float* __restrict__ x,
                                                  float* __restrict__ mu, float* __restrict__ rsig){
  int pos = blockIdx.x*256 + threadIdx.x;
  int b = pos >> 14, l = pos & (L-1);
  const float* xp = x + (size_t)b*C0*L + l;
  float s=0.f, ss=0.f;
  for (int c=0;c<C0;++c){ float v = xp[(size_t)c*L]; s += v; ss += v*v; }
  float m = s*(1.f/C0);
  float var = ss*(1.f/C0) - m*m;
  mu[pos]=m; rsig[pos]=rsqrtf(var + 1e-5f);
}

// ---------------- weight packing (fp32 -> bf16, [Mpad][Kpad] row-major) ----------------
__global__ void packw_k(const float* __restrict__ W, const float* __restrict__ lnw,
                        ushort* __restrict__ out, int Csrc, int O, int Kpad, int total){
  int idx = blockIdx.x*256 + threadIdx.x;
  if (idx >= total) return;
  int m = idx / Kpad, k = idx - m*Kpad;
  float v = 0.f;
  if (k < Csrc && m < O){ v = W[(size_t)m*Csrc + k]; if (lnw) v *= lnw[k]; }
  out[idx] = f2u(v);
}

// A[o]=sum_c W[o,c]*lnw[c]; B[o]=sum_c W[o,c]*lnb[c]  (padded to Opad)
__global__ void prepab_k(const float* __restrict__ W, const float* __restrict__ lnw,
                         const float* __restrict__ lnb, float* __restrict__ A, float* __restrict__ Bv,
                         int Cc, int O, int Opad){
  int o = blockIdx.x*256 + threadIdx.x;
  if (o >= Opad) return;
  float a=0.f,b=0.f;
  if (o < O){
    const float* wr = W + (size_t)o*Cc;
    for (int c=0;c<Cc;++c){ float w=wr[c]; a = fmaf(w, lnw[c], a); b = fmaf(w, lnb[c], b); }
  }
  A[o]=a; Bv[o]=b;
}

// ---------------- panel-persistent MFMA GEMM ----------------
// OUT[o,pos] = epilogue( sum_k A[o,k]*X[k,pos] ).  A: bf16 [Mpad][KPAD] row-major.
// One block owns a 128-position panel; X panel staged to LDS once per KPASS;
// M-loop (MCH chunks of 64 rows) reads A-frags from L1/L2 registers-direct.
// EPI 0: LN  -> bf16 out = rs*(acc - mu*Avec[o]) + Bvec[o]
// EPI 1: RES -> f32 out = res + acc
// EPI 2: ADD -> f32 out += acc
template<int EPI, bool BF32, int KT_RES, int KPASS, int MCH>
__global__ __launch_bounds__(256) void gemmp_k(
    const ushort* __restrict__ A, int aBatchStride,
    const void* __restrict__ X, size_t xBS,
    const float* __restrict__ mu, const float* __restrict__ rs,
    const float* __restrict__ Avec, const float* __restrict__ Bvec,
    const float* __restrict__ res,
    void* __restrict__ outp, int Orows, int Ovalid)
{
  constexpr int KPAD = KT_RES*KPASS*32;
  __shared__ ushort xt[KT_RES][128][40];
  const int tid  = threadIdx.x;
  const int lane = tid & 63, w = tid >> 6;
  const int nblk = blockIdx.x;
  const int b    = nblk >> 7;
  const int l0   = (nblk & 127) * 128;
  const int mbase= blockIdx.y * (MCH*64);
  const int g16  = lane >> 4, c16 = lane & 15;

  const ushort* Ab = A + (size_t)b * aBatchStride;

  f32x4 acc[MCH][4][2];
  #pragma unroll
  for (int mc=0; mc<MCH; ++mc)
    #pragma unroll
    for (int mi=0; mi<4; ++mi)
      #pragma unroll
      for (int ni=0; ni<2; ++ni){ f32x4 z = {0.f,0.f,0.f,0.f}; acc[mc][mi][ni] = z; }

  const int sc2  = (tid & 15) * 2;
  const int spos = (tid >> 4) * 8;

  for (int kp = 0; kp < KPASS; ++kp){
    if (kp) __syncthreads();
    // ---- stage KT_RES k-tiles of the X panel into LDS ----
    #pragma unroll
    for (int kt = 0; kt < KT_RES; ++kt){
      const int kbase = kp*(KT_RES*32) + kt*32;
      ushort ua[8], ub[8];
      if (BF32){
        const float* xr = (const float*)X + (size_t)b*xBS + (size_t)(kbase+sc2)*L + l0 + spos;
        float fa[8], fb[8];
        *(float4*)&fa[0] = *(const float4*)xr;       *(float4*)&fa[4] = *(const float4*)(xr+4);
        *(float4*)&fb[0] = *(const float4*)(xr+L);   *(float4*)&fb[4] = *(const float4*)(xr+L+4);
        #pragma unroll
        for (int j=0;j<8;++j){ ua[j]=f2u(fa[j]); ub[j]=f2u(fb[j]); }
      } else {
        const ushort* xr = (const ushort*)X + (size_t)b*xBS + (size_t)(kbase+sc2)*L + l0 + spos;
        uint4 ra = *(const uint4*)xr; uint4 rb = *(const uint4*)(xr+L);
        const ushort* pa = (const ushort*)&ra; const ushort* pb = (const ushort*)&rb;
        #pragma unroll
        for (int j=0;j<8;++j){ ua[j]=pa[j]; ub[j]=pb[j]; }
      }
      #pragma unroll
      for (int j=0;j<8;++j){ ushort2 t2; t2.x = ua[j]; t2.y = ub[j]; *(ushort2*)&xt[kt][spos+j][sc2] = t2; }
    }
    __syncthreads();

    // ---- M-loop: A-frags from global (L1-resident per chunk), B from LDS ----
    #pragma unroll
    for (int mc = 0; mc < MCH; ++mc){
      #pragma unroll
      for (int kt = 0; kt < KT_RES; ++kt){
        const int kbase = kp*(KT_RES*32) + kt*32;
        bf16x8 af[4];
        #pragma unroll
        for (int mi=0; mi<4; ++mi)
          af[mi] = ld_bf8(Ab + (size_t)(mbase + mc*64 + mi*16 + c16)*KPAD + kbase + g16*8);
        bf16x8 bv[2];
        #pragma unroll
        for (int ni=0; ni<2; ++ni)
          bv[ni] = ld_bf8(&xt[kt][w*32 + ni*16 + c16][g16*8]);
        #pragma unroll
        for (int mi=0; mi<4; ++mi)
          #pragma unroll
          for (int ni=0; ni<2; ++ni)
            acc[mc][mi][ni] = mfma16(af[mi], bv[ni], acc[mc][mi][ni]);
      }
    }
  }

  // ---- epilogue ----
  const int rowOff = g16*4;
  #pragma unroll
  for (int mc = 0; mc < MCH; ++mc){
    #pragma unroll
    for (int ni=0; ni<2; ++ni){
      int nl = w*32 + ni*16 + c16;
      int l  = l0 + nl;
      float muv=0.f, rsv=0.f;
      if (EPI == 0){ int pos = b*L + l; muv = mu[pos]; rsv = rs[pos]; }
      #pragma unroll
      for (int mi=0; mi<4; ++mi){
        #pragma unroll
        for (int r=0; r<4; ++r){
          int o = mbase + mc*64 + mi*16 + rowOff + r;
          float a = acc[mc][mi][ni][r];
          if (EPI == 0){
            if (o < Ovalid){
              float vv = rsv*(a - muv*Avec[o]) + Bvec[o];
              ((ushort*)outp)[((size_t)b*Orows + o)*L + l] = f2u(vv);
            }
          } else if (EPI == 1){
            size_t idx = ((size_t)b*Orows + o)*L + l;
            ((float*)outp)[idx] = res[idx] + a;
          } else {
            size_t idx = ((size_t)b*Orows + o)*L + l;
            ((float*)outp)[idx] += a;
          }
        }
      }
    }
  }
}

// ---------------- depthwise 3x3, 8 px/thread, bf16, optional sum-of-squares ----------------
__global__ __launch_bounds__(256) void dwconv8_k(const ushort* __restrict__ in, const float* __restrict__ w9,
    ushort* __restrict__ out, float* __restrict__ ss, int Cc, int nss){
  int e  = blockIdx.x*256 + threadIdx.x;
  int bc = e >> 11;
  int p  = (e & 2047) * 8;
  int c  = bc % Cc, b = bc / Cc;
  int y  = p >> 7, x0 = p & 127;
  const ushort* ip = in + (size_t)bc*L;
  float w[9];
  #pragma unroll
  for (int i=0;i<9;++i) w[i] = w9[c*9+i];
  float v[3][10];
  #pragma unroll
  for (int r=0;r<3;++r){
    int yy = y + r - 1;
    if ((unsigned)yy >= IMG){
      #pragma unroll
      for (int j=0;j<10;++j) v[r][j]=0.f;
    } else {
      const ushort* rp = ip + yy*IMG + x0;
      uint4 cv = *(const uint4*)rp; const ushort* us = (const ushort*)&cv;
      #pragma unroll
      for (int j=0;j<8;++j) v[r][j+1] = u2f(us[j]);
      v[r][0] = (x0>0)   ? u2f(rp[-1]) : 0.f;
      v[r][9] = (x0<120) ? u2f(rp[8])  : 0.f;
    }
  }
  float sq = 0.f; ushort o8[8];
  #pragma unroll
  for (int j=0;j<8;++j){
    float a = 0.f;
    #pragma unroll
    for (int r=0;r<3;++r)
      #pragma unroll
      for (int dx=0;dx<3;++dx) a = fmaf(w[r*3+dx], v[r][j+dx], a);
    o8[j] = f2u(a); sq += a*a;
  }
  *(uint4*)(out + (size_t)bc*L + p) = *(const uint4*)o8;
  if (ss != nullptr && c < nss){
    #pragma unroll
    for (int off=32; off>0; off>>=1) sq += __shfl_xor(sq, off, 64);
    __shared__ float red[4];
    int wid = threadIdx.x >> 6;
    if ((threadIdx.x & 63)==0) red[wid]=sq;
    __syncthreads();
    if (threadIdx.x==0) atomicAdd(&ss[b*nss + c], red[0]+red[1]+red[2]+red[3]);
  }
}

// ---------------- QK^T via MFMA, k-split over L ----------------
__global__ __launch_bounds__(64) void qk_mfma_k(const ushort* __restrict__ qb, const ushort* __restrict__ kvb,
                                                float* __restrict__ P){
  int ks = blockIdx.x, bh = blockIdx.y;
  int b = bh >> 2, h = bh & 3;
  int lane = threadIdx.x, g16 = lane>>4, c16 = lane&15;
  const ushort* qbase = qb  + ((size_t)b*C0      + h*CHN)*L;
  const ushort* kbse  = kvb + ((size_t)b*(2*C0)  + h*CHN)*L;
  f32x4 acc[3][3];
  #pragma unroll
  for (int i=0;i<3;++i)
    #pragma unroll
    for (int j=0;j<3;++j){ f32x4 z={0.f,0.f,0.f,0.f}; acc[i][j]=z; }
  int k0 = ks * (L/KSPLIT);
  for (int kk=0; kk<(L/KSPLIT)/32; ++kk){
    int kb = k0 + kk*32;
    bf16x8 af[3], bv[3];
    #pragma unroll
    for (int i=0;i<3;++i){
      af[i] = ld_bf8(qbase + (size_t)(i*16+c16)*L + kb + g16*8);
      bv[i] = ld_bf8(kbse  + (size_t)(i*16+c16)*L + kb + g16*8);
    }
    #pragma unroll
    for (int mi=0;mi<3;++mi)
      #pragma unroll
      for (int ni=0;ni<3;++ni)
        acc[mi][ni] = mfma16(af[mi], bv[ni], acc[mi][ni]);
  }
  float* Pp = P + ((size_t)ks*(BATCH*NH) + bh)*CHN*CHN;
  #pragma unroll
  for (int mi=0;mi<3;++mi)
    #pragma unroll
    for (int ni=0;ni<3;++ni)
      #pragma unroll
      for (int r=0;r<4;++r){
        int m = mi*16 + g16*4 + r, n = ni*16 + c16;
        Pp[m*CHN + n] = acc[mi][ni][r];
      }
}

__global__ void reduceS_k(const float* __restrict__ P, float* __restrict__ S){
  int i = blockIdx.x*256 + threadIdx.x;
  if (i >= BATCH*NH*CHN*CHN) return;
  float s = 0.f;
  for (int ks=0; ks<KSPLIT; ++ks) s += P[(size_t)ks*(BATCH*NH*CHN*CHN) + i];
  S[i] = s;
}

// ---------------- softmax + gating + Wca modulation: one wave per (b,h,c) row ----------------
__global__ __launch_bounds__(64) void gating_k(const float* __restrict__ S, const float* __restrict__ qss,
                         const float* __restrict__ kss, const float* __restrict__ temp,
                         const float* __restrict__ Wca, float* __restrict__ attnF){
  int blk = blockIdx.x;                 // bh*CHN + c
  int c  = blk % CHN; int bh = blk / CHN;
  int h  = bh & 3, b = bh >> 2;
  int d  = threadIdx.x;                 // lane; active for d < 48
  bool act = (d < CHN);

  float T  = temp[h];
  float nq = sqrtf(qss[b*C0 + h*CHN + c]);
  float rq = 1.f/fmaxf(nq, 1e-12f);
  float rk = 0.f, sv = 0.f;
  if (act){
    float nk = sqrtf(kss[b*C0 + h*CHN + d]);
    rk = 1.f/fmaxf(nk, 1e-12f);
    sv = S[((size_t)bh*CHN + c)*CHN + d];
  }
  float raw = act ? sv*rq*rk*T : -1e30f;

  // softmax across 48 active lanes
  float mx = raw;
  #pragma unroll
  for (int off=32; off>0; off>>=1) mx = fmaxf(mx, __shfl_xor(mx, off, 64));
  float e = act ? expf(raw - mx) : 0.f;
  float sum = e;
  #pragma unroll
  for (int off=32; off>0; off>>=1) sum += __shfl_xor(sum, off, 64);
  float a0 = e / sum;

  // a1 = gelu(relu(raw)^2) * relu(raw)^2, broadcast via LDS
  float r = fmaxf(raw, 0.f); r = r*r;
  float a1 = gelu_exact(r)*r;
  __shared__ float a1s[CHN];
  if (act) a1s[d] = a1;
  __syncthreads();

  if (!act) return;
  float s1 = 0.f, s2 = 0.f;
  const float* w1 = Wca + (size_t)d*CHN;
  const float* w2 = Wca + (size_t)(d+CHN)*CHN;
  #pragma unroll
  for (int j=0;j<CHN;++j){
    float aj = a1s[j];
    s1 = fmaf(w1[j], aj, s1);
    s2 = fmaf(w2[j], aj, s2);
  }
  attnF[((size_t)bh*CHN + c)*CHN + d] = a0*(1.f+s1) + s2;
}

// Mtb[b][o][dfull] = sum_c Wproj[o][h*48+c] * attnF[b][h][c][d]   (bf16)
__global__ void mt_k(const float* __restrict__ Wproj, const float* __restrict__ attnF,
                     ushort* __restrict__ Mtb){
  int idx = blockIdx.x*256 + threadIdx.x;
  if (idx >= BATCH*C0*C0) return;
  int d = idx % C0; int o = (idx / C0) % C0; int b = idx / (C0*C0);
  int h = d / CHN, dd = d % CHN;
  float s=0.f;
  for (int c=0;c<CHN;++c)
    s = fmaf(Wproj[(size_t)o*C0 + h*CHN + c],
             attnF[(((size_t)(b*NH+h))*CHN + c)*CHN + dd], s);
  Mtb[idx] = f2u(s);
}

// ---------------- GDFN fused dwconv + gelu gate (writes 512 rows/b, pad rows zero) ----------------
__global__ __launch_bounds__(256) void ffn8_k(const ushort* __restrict__ hidden, const float* __restrict__ w9,
                                              ushort* __restrict__ g){
  int e  = blockIdx.x*256 + threadIdx.x;
  int bg = e >> 11;
  int p  = (e & 2047) * 8;
  int go = bg & 511, b = bg >> 9;
  ushort* op = g + (size_t)bg*L + p;
  if (go >= HID){ uint4 z = {0,0,0,0}; *(uint4*)op = z; return; }
  int y = p >> 7, x0 = p & 127;
  const ushort* i1 = hidden + ((size_t)b*HID2 + go)*L;
  const ushort* i2 = i1 + (size_t)HID*L;
  float w1[9], w2[9];
  #pragma unroll
  for (int i=0;i<9;++i){ w1[i] = w9[go*9+i]; w2[i] = w9[(HID+go)*9+i]; }
  float v1[3][10], v2[3][10];
  #pragma unroll
  for (int r=0;r<3;++r){
    int yy = y + r - 1;
    if ((unsigned)yy >= IMG){
      #pragma unroll
      for (int j=0;j<10;++j){ v1[r][j]=0.f; v2[r][j]=0.f; }
    } else {
      const ushort* rp1 = i1 + yy*IMG + x0;
      const ushort* rp2 = i2 + yy*IMG + x0;
      uint4 c1 = *(const uint4*)rp1; const ushort* u1 = (const ushort*)&c1;
      uint4 c2 = *(const uint4*)rp2; const ushort* u2 = (const ushort*)&c2;
      #pragma unroll
      for (int j=0;j<8;++j){ v1[r][j+1] = u2f(u1[j]); v2[r][j+1] = u2f(u2[j]); }
      v1[r][0] = (x0>0)   ? u2f(rp1[-1]) : 0.f;
      v1[r][9] = (x0<120) ? u2f(rp1[8])  : 0.f;
      v2[r][0] = (x0>0)   ? u2f(rp2[-1]) : 0.f;
      v2[r][9] = (x0<120) ? u2f(rp2[8])  : 0.f;
    }
  }
  ushort o8[8];
  #pragma unroll
  for (int j=0;j<8;++j){
    float d1=0.f, d2=0.f;
    #pragma unroll
    for (int r=0;r<3;++r)
      #pragma unroll
      for (int dx=0;dx<3;++dx){
        d1 = fmaf(w1[r*3+dx], v1[r][j+dx], d1);
        d2 = fmaf(w2[r*3+dx], v2[r][j+dx], d2);
      }
    o8[j] = f2u(gelu_exact(d1)*d2);
  }
  *(uint4*)op = *(const uint4*)o8;
}

extern "C" void kernel_launch(void* const* d_in, const int* in_sizes, int n_in,
                              void* d_out, int out_size, void* d_ws, size_t ws_size,
                              hipStream_t stream){
  (void)in_sizes; (void)n_in; (void)out_size; (void)ws_size;
  const float* lr    = (const float*)d_in[0];
  const float* ref   = (const float*)d_in[1];
  const float* ln1w  = (const float*)d_in[2];
  const float* ln1b  = (const float*)d_in[3];
  const float* lnrw  = (const float*)d_in[4];
  const float* lnrb  = (const float*)d_in[5];
  const float* ln2w  = (const float*)d_in[6];
  const float* ln2b  = (const float*)d_in[7];
  const float* Wq    = (const float*)d_in[8];
  const float* qdw   = (const float*)d_in[9];
  const float* Wkv   = (const float*)d_in[10];
  const float* kvdw  = (const float*)d_in[11];
  const float* Wproj = (const float*)d_in[12];
  const float* Wca   = (const float*)d_in[13];
  const float* temp  = (const float*)d_in[14];
  const float* Wpin  = (const float*)d_in[15];
  const float* ffndw = (const float*)d_in[16];
  const float* Wpout = (const float*)d_in[17];
  float* out = (float*)d_out;

  char* ws = (char*)d_ws;
  size_t off = 0;
  auto alloc = [&](size_t bytes)->void*{ void* p = ws + off; off += (bytes + 255) & ~(size_t)255; return p; };

  ushort* Aqbf   = (ushort*)alloc((size_t)192*192*2);
  ushort* Akvbf  = (ushort*)alloc((size_t)384*192*2);
  ushort* Apinbf = (ushort*)alloc((size_t)1024*192*2);
  ushort* Apoutbf= (ushort*)alloc((size_t)192*512*2);
  ushort* Mtb    = (ushort*)alloc((size_t)BATCH*C0*C0*2);
  float* Aqv  = (float*)alloc(192*4);   float* Bqv  = (float*)alloc(192*4);
  float* Akvv = (float*)alloc(384*4);   float* Bkvv = (float*)alloc(384*4);
  float* Apinv= (float*)alloc(1024*4);  float* Bpinv= (float*)alloc(1024*4);
  float* mu_lr = (float*)alloc((size_t)BL*4);  float* rs_lr = (float*)alloc((size_t)BL*4);
  float* mu_rf = (float*)alloc((size_t)BL*4);  float* rs_rf = (float*)alloc((size_t)BL*4);
  float* mu_o  = (float*)alloc((size_t)BL*4);  float* rs_o  = (float*)alloc((size_t)BL*4);
  float* qss   = (float*)alloc((size_t)BATCH*C0*4);
  float* kss   = (float*)alloc((size_t)BATCH*C0*4);
  float* S     = (float*)alloc((size_t)BATCH*NH*CHN*CHN*4);
  float* attnF = (float*)alloc((size_t)BATCH*NH*CHN*CHN*4);
  char*  pool  = (char*)alloc((size_t)109051904);

  ushort* q_pre  = (ushort*)(pool);                       // 12,582,912
  ushort* kv_pre = (ushort*)(pool + 12582912);            // 25,165,824
  ushort* qb     = (ushort*)(pool + 37748736);            // 12,582,912
  ushort* kvb    = (ushort*)(pool + 50331648);            // 25,165,824
  float*  Pp     = (float*) (pool);                       // 9,437,184 (overlays q_pre, dead then)
  ushort* hidden = (ushort*)(pool);                       // 66,846,720 (overlays first 4, dead then)
  ushort* g      = (ushort*)(pool + 75497472);            // 33,554,432

  hipMemsetAsync(qss, 0, (size_t)BATCH*C0*4, stream);
  hipMemsetAsync(kss, 0, (size_t)BATCH*C0*4, stream);

  // weight prep
  packw_k<<<(192*192+255)/256,256,0,stream>>>(Wq,   ln1w, Aqbf,   192, 192, 192, 192*192);
  packw_k<<<(384*192+255)/256,256,0,stream>>>(Wkv,  lnrw, Akvbf,  192, 384, 192, 384*192);
  packw_k<<<(1024*192+255)/256,256,0,stream>>>(Wpin, ln2w, Apinbf, 192, 1020, 192, 1024*192);
  packw_k<<<(192*512+255)/256,256,0,stream>>>(Wpout, nullptr, Apoutbf, 510, 192, 512, 192*512);
  prepab_k<<<1,256,0,stream>>>(Wq,  ln1w, ln1b, Aqv,  Bqv,  192, 192, 192);
  prepab_k<<<2,256,0,stream>>>(Wkv, lnrw, lnrb, Akvv, Bkvv, 192, 384, 384);
  prepab_k<<<4,256,0,stream>>>(Wpin,ln2w, ln2b, Apinv,Bpinv,192, 1020, 1024);

  // LN stats
  ln_stats_k<<<BL/256,256,0,stream>>>(lr,  mu_lr, rs_lr);
  ln_stats_k<<<BL/256,256,0,stream>>>(ref, mu_rf, rs_rf);

  // fused LN + 1x1 conv GEMMs (panel-persistent MFMA)
  gemmp_k<0,true,3,2,1><<<dim3(256,3),256,0,stream>>>(Aqbf, 0, lr, (size_t)C0*L,
      mu_lr, rs_lr, Aqv, Bqv, nullptr, q_pre, 192, 192);
  gemmp_k<0,true,3,2,2><<<dim3(256,3),256,0,stream>>>(Akvbf, 0, ref, (size_t)C0*L,
      mu_rf, rs_rf, Akvv, Bkvv, nullptr, kv_pre, 384, 384);

  // depthwise convs + l2 sum-of-squares
  dwconv8_k<<<(BATCH*192*L/8)/256,256,0,stream>>>(q_pre,  qdw,  qb,  qss, 192, 192);
  dwconv8_k<<<(BATCH*384*L/8)/256,256,0,stream>>>(kv_pre, kvdw, kvb, kss, 384, 192);

  // attention core
  qk_mfma_k<<<dim3(KSPLIT, BATCH*NH),64,0,stream>>>(qb, kvb, Pp);
  reduceS_k<<<(BATCH*NH*CHN*CHN+255)/256,256,0,stream>>>(Pp, S);
  gating_k<<<BATCH*NH*CHN,64,0,stream>>>(S, qss, kss, temp, Wca, attnF);
  mt_k<<<(BATCH*C0*C0+255)/256,256,0,stream>>>(Wproj, attnF, Mtb);

  // out = lr + Mt . v
  gemmp_k<1,false,3,2,1><<<dim3(256,3),256,0,stream>>>(Mtb, 192*192, kvb + (size_t)C0*L, (size_t)2*C0*L,
      nullptr, nullptr, nullptr, nullptr, lr, out, 192, 192);

  // GDFN
  ln_stats_k<<<BL/256,256,0,stream>>>(out, mu_o, rs_o);
  gemmp_k<0,true,3,2,2><<<dim3(256,8),256,0,stream>>>(Apinbf, 0, out, (size_t)C0*L,
      mu_o, rs_o, Apinv, Bpinv, nullptr, hidden, 1020, 1020);
  ffn8_k<<<(BATCH*512*L/8)/256,256,0,stream>>>(hidden, ffndw, g);
  gemmp_k<2,false,4,4,1><<<dim3(256,3),256,0,stream>>>(Apoutbf, 0, g, (size_t)512*L,
      nullptr, nullptr, nullptr, nullptr, nullptr, out, 192, 192);
}

// Round 5
// 440.672 us; speedup vs baseline: 3.2128x; 1.0416x over previous
//
#include <hip/hip_runtime.h>
#include <hip/hip_bf16.h>
#include <math.h>

#define L     16384
#define IMG   128
#define BATCH 2
#define C0    192
#define NH    4
#define CHN   48
#define HID   510
#define HID2  1020
#define BL    (BATCH*L)
#define KSPLIT 64

typedef float  f32x4  __attribute__((ext_vector_type(4)));
typedef __bf16 bf16x8 __attribute__((ext_vector_type(8)));

union UB16 { uint4 u; bf16x8 v; };

__device__ __forceinline__ bf16x8 ld_bf8(const ushort* p){ UB16 x; x.u = *(const uint4*)p; return x.v; }
__device__ __forceinline__ f32x4 mfma16(bf16x8 a, bf16x8 b, f32x4 c){
  return __builtin_amdgcn_mfma_f32_16x16x32_bf16(a, b, c, 0, 0, 0);
}
__device__ __forceinline__ float u2f(ushort u){ union{unsigned u; float f;} x; x.u = ((unsigned)u)<<16; return x.f; }
__device__ __forceinline__ ushort f2u(float f){ __hip_bfloat16 h = __float2bfloat16(f); return *reinterpret_cast<ushort*>(&h); }
__device__ __forceinline__ float gelu_exact(float x){ return 0.5f*x*(1.0f+erff(x*0.70710678118654752f)); }

// ---------------- per-position channel-LN stats ----------------
__global__ __launch_bounds__(256) void ln_stats_k(const float* __restrict__ x,
                                                  float* __restrict__ mu, float* __restrict__ rsig){
  int pos = blockIdx.x*256 + threadIdx.x;
  int b = pos >> 14, l = pos & (L-1);
  const float* xp = x + (size_t)b*C0*L + l;
  float s=0.f, ss=0.f;
  for (int c=0;c<C0;++c){ float v = xp[(size_t)c*L]; s += v; ss += v*v; }
  float m = s*(1.f/C0);
  float var = ss*(1.f/C0) - m*m;
  mu[pos]=m; rsig[pos]=rsqrtf(var + 1e-5f);
}

// ---------------- weight packing (fp32 -> bf16, [Mpad][Kpad] row-major) ----------------
__global__ void packw_k(const float* __restrict__ W, const float* __restrict__ lnw,
                        ushort* __restrict__ out, int Csrc, int O, int Kpad, int total){
  int idx = blockIdx.x*256 + threadIdx.x;
  if (idx >= total) return;
  int m = idx / Kpad, k = idx - m*Kpad;
  float v = 0.f;
  if (k < Csrc && m < O){ v = W[(size_t)m*Csrc + k]; if (lnw) v *= lnw[k]; }
  out[idx] = f2u(v);
}

// A[o]=sum_c W[o,c]*lnw[c]; B[o]=sum_c W[o,c]*lnb[c]  (padded to Opad)
__global__ void prepab_k(const float* __restrict__ W, const float* __restrict__ lnw,
                         const float* __restrict__ lnb, float* __restrict__ A, float* __restrict__ Bv,
                         int Cc, int O, int Opad){
  int o = blockIdx.x*256 + threadIdx.x;
  if (o >= Opad) return;
  float a=0.f,b=0.f;
  if (o < O){
    const float* wr = W + (size_t)o*Cc;
    for (int c=0;c<Cc;++c){ float w=wr[c]; a = fmaf(w, lnw[c], a); b = fmaf(w, lnb[c], b); }
  }
  A[o]=a; Bv[o]=b;
}

// ---------------- pipelined 2-phase MFMA GEMM ----------------
// OUT[o,pos] = epilogue( sum_k A[o,k]*X[k,pos] ).  A bf16 [Mpad][KPAD] row-major.
// X double-buffered in LDS (transposed), A-frags register-prefetched 1 k-step ahead.
// WR=2: 128x128 tile (4 waves 2x2, 64x64 each). WR=1: 64x128 tile (4 waves share rows, 32 cols each).
// EPI 0: LN bf16 out; EPI 1: f32 out = res+acc; EPI 2: f32 out += acc
template<int EPI, int WR, int KPAD, bool BF32>
__global__ __launch_bounds__(256, WR==2?3:4) void gemm2_k(
    const ushort* __restrict__ A, int aBatchStride,
    const void* __restrict__ X, size_t xBS,
    const float* __restrict__ mu, const float* __restrict__ rs,
    const float* __restrict__ Avec, const float* __restrict__ Bvec,
    const float* __restrict__ res,
    void* __restrict__ outp, int Orows, int Ovalid)
{
  constexpr int BM  = WR*64;
  constexpr int NFR = (WR==2)?4:2;
  constexpr int KS  = KPAD/32;
  __shared__ ushort xt[2][128][40];

  const int tid = threadIdx.x, lane = tid & 63, w = tid >> 6;
  const int b   = blockIdx.x >> 7;
  const int l0  = (blockIdx.x & 127) * 128;
  const int mbase = blockIdx.y * BM;
  const int g16 = lane >> 4, c16 = lane & 15;
  const int wrbase = (WR==2) ? (w>>1)*64 : 0;
  const int wcbase = (WR==2) ? (w&1)*64 : w*32;

  const ushort* Ab = A + (size_t)b*aBatchStride + (size_t)(mbase + wrbase)*KPAD;
  const int sc2 = (tid & 15) * 2;
  const int spos = (tid >> 4) * 8;

  f32x4 acc[4][NFR];
  #pragma unroll
  for (int mi=0; mi<4; ++mi)
    #pragma unroll
    for (int ni=0; ni<NFR; ++ni){ f32x4 z = {0.f,0.f,0.f,0.f}; acc[mi][ni] = z; }

  // ---- prologue: stage k-chunk 0, preload A-frags for step 0 ----
  ushort ua[8], ub[8];
  if (BF32){
    const float* xr = (const float*)X + (size_t)b*xBS + (size_t)sc2*L + l0 + spos;
    float fa[8], fb[8];
    *(float4*)&fa[0] = *(const float4*)xr;       *(float4*)&fa[4] = *(const float4*)(xr+4);
    *(float4*)&fb[0] = *(const float4*)(xr+L);   *(float4*)&fb[4] = *(const float4*)(xr+L+4);
    #pragma unroll
    for (int j=0;j<8;++j){ ua[j]=f2u(fa[j]); ub[j]=f2u(fb[j]); }
  } else {
    const ushort* xr = (const ushort*)X + (size_t)b*xBS + (size_t)sc2*L + l0 + spos;
    uint4 ra = *(const uint4*)xr; uint4 rb = *(const uint4*)(xr+L);
    const ushort* pa = (const ushort*)&ra; const ushort* pb = (const ushort*)&rb;
    #pragma unroll
    for (int j=0;j<8;++j){ ua[j]=pa[j]; ub[j]=pb[j]; }
  }
  bf16x8 afc[4];
  #pragma unroll
  for (int mi=0; mi<4; ++mi)
    afc[mi] = ld_bf8(Ab + (size_t)(mi*16 + c16)*KPAD + g16*8);
  #pragma unroll
  for (int j=0;j<8;++j){ ushort2 t2; t2.x=ua[j]; t2.y=ub[j]; *(ushort2*)&xt[0][spos+j][sc2] = t2; }
  __syncthreads();

  // ---- main loop: one barrier per k-step, prefetch X & A for k+1 ----
  #pragma unroll
  for (int ks=0; ks<KS; ++ks){
    ushort na[8], nb[8]; bf16x8 afn[4];
    if (ks+1 < KS){
      const int kb = (ks+1)*32;
      if (BF32){
        const float* xr = (const float*)X + (size_t)b*xBS + (size_t)(kb+sc2)*L + l0 + spos;
        float fa[8], fb[8];
        *(float4*)&fa[0] = *(const float4*)xr;       *(float4*)&fa[4] = *(const float4*)(xr+4);
        *(float4*)&fb[0] = *(const float4*)(xr+L);   *(float4*)&fb[4] = *(const float4*)(xr+L+4);
        #pragma unroll
        for (int j=0;j<8;++j){ na[j]=f2u(fa[j]); nb[j]=f2u(fb[j]); }
      } else {
        const ushort* xr = (const ushort*)X + (size_t)b*xBS + (size_t)(kb+sc2)*L + l0 + spos;
        uint4 ra = *(const uint4*)xr; uint4 rb = *(const uint4*)(xr+L);
        const ushort* pa = (const ushort*)&ra; const ushort* pb = (const ushort*)&rb;
        #pragma unroll
        for (int j=0;j<8;++j){ na[j]=pa[j]; nb[j]=pb[j]; }
      }
      #pragma unroll
      for (int mi=0; mi<4; ++mi)
        afn[mi] = ld_bf8(Ab + (size_t)(mi*16 + c16)*KPAD + kb + g16*8);
    }

    bf16x8 bv[NFR];
    #pragma unroll
    for (int ni=0; ni<NFR; ++ni)
      bv[ni] = ld_bf8(&xt[ks&1][wcbase + ni*16 + c16][g16*8]);
    #pragma unroll
    for (int mi=0; mi<4; ++mi)
      #pragma unroll
      for (int ni=0; ni<NFR; ++ni)
        acc[mi][ni] = mfma16(afc[mi], bv[ni], acc[mi][ni]);

    if (ks+1 < KS){
      #pragma unroll
      for (int j=0;j<8;++j){ ushort2 t2; t2.x=na[j]; t2.y=nb[j]; *(ushort2*)&xt[(ks+1)&1][spos+j][sc2] = t2; }
      __syncthreads();
      #pragma unroll
      for (int mi=0; mi<4; ++mi) afc[mi] = afn[mi];
    }
  }

  // ---- epilogue ----
  #pragma unroll
  for (int ni=0; ni<NFR; ++ni){
    int nl = wcbase + ni*16 + c16;
    int l  = l0 + nl;
    float muv=0.f, rsv=0.f;
    if (EPI == 0){ int pos = b*L + l; muv = mu[pos]; rsv = rs[pos]; }
    #pragma unroll
    for (int mi=0; mi<4; ++mi){
      #pragma unroll
      for (int r=0; r<4; ++r){
        int o = mbase + wrbase + mi*16 + g16*4 + r;
        float a = acc[mi][ni][r];
        if (EPI == 0){
          if (o < Ovalid){
            float vv = rsv*(a - muv*Avec[o]) + Bvec[o];
            ((ushort*)outp)[((size_t)b*Orows + o)*L + l] = f2u(vv);
          }
        } else if (EPI == 1){
          size_t idx = ((size_t)b*Orows + o)*L + l;
          ((float*)outp)[idx] = res[idx] + a;
        } else {
          size_t idx = ((size_t)b*Orows + o)*L + l;
          ((float*)outp)[idx] += a;
        }
      }
    }
  }
}

// ---------------- depthwise 3x3, 8 px/thread, bf16, optional sum-of-squares ----------------
__global__ __launch_bounds__(256) void dwconv8_k(const ushort* __restrict__ in, const float* __restrict__ w9,
    ushort* __restrict__ out, float* __restrict__ ss, int Cc, int nss){
  int e  = blockIdx.x*256 + threadIdx.x;
  int bc = e >> 11;
  int p  = (e & 2047) * 8;
  int c  = bc % Cc, b = bc / Cc;
  int y  = p >> 7, x0 = p & 127;
  const ushort* ip = in + (size_t)bc*L;
  float w[9];
  #pragma unroll
  for (int i=0;i<9;++i) w[i] = w9[c*9+i];
  float v[3][10];
  #pragma unroll
  for (int r=0;r<3;++r){
    int yy = y + r - 1;
    if ((unsigned)yy >= IMG){
      #pragma unroll
      for (int j=0;j<10;++j) v[r][j]=0.f;
    } else {
      const ushort* rp = ip + yy*IMG + x0;
      uint4 cv = *(const uint4*)rp; const ushort* us = (const ushort*)&cv;
      #pragma unroll
      for (int j=0;j<8;++j) v[r][j+1] = u2f(us[j]);
      v[r][0] = (x0>0)   ? u2f(rp[-1]) : 0.f;
      v[r][9] = (x0<120) ? u2f(rp[8])  : 0.f;
    }
  }
  float sq = 0.f; ushort o8[8];
  #pragma unroll
  for (int j=0;j<8;++j){
    float a = 0.f;
    #pragma unroll
    for (int r=0;r<3;++r)
      #pragma unroll
      for (int dx=0;dx<3;++dx) a = fmaf(w[r*3+dx], v[r][j+dx], a);
    o8[j] = f2u(a); sq += a*a;
  }
  *(uint4*)(out + (size_t)bc*L + p) = *(const uint4*)o8;
  if (ss != nullptr && c < nss){
    #pragma unroll
    for (int off=32; off>0; off>>=1) sq += __shfl_xor(sq, off, 64);
    __shared__ float red[4];
    int wid = threadIdx.x >> 6;
    if ((threadIdx.x & 63)==0) red[wid]=sq;
    __syncthreads();
    if (threadIdx.x==0) atomicAdd(&ss[b*nss + c], red[0]+red[1]+red[2]+red[3]);
  }
}

// ---------------- QK^T via MFMA, k-split over L ----------------
__global__ __launch_bounds__(64) void qk_mfma_k(const ushort* __restrict__ qb, const ushort* __restrict__ kvb,
                                                float* __restrict__ P){
  int ks = blockIdx.x, bh = blockIdx.y;
  int b = bh >> 2, h = bh & 3;
  int lane = threadIdx.x, g16 = lane>>4, c16 = lane&15;
  const ushort* qbase = qb  + ((size_t)b*C0      + h*CHN)*L;
  const ushort* kbse  = kvb + ((size_t)b*(2*C0)  + h*CHN)*L;
  f32x4 acc[3][3];
  #pragma unroll
  for (int i=0;i<3;++i)
    #pragma unroll
    for (int j=0;j<3;++j){ f32x4 z={0.f,0.f,0.f,0.f}; acc[i][j]=z; }
  int k0 = ks * (L/KSPLIT);
  for (int kk=0; kk<(L/KSPLIT)/32; ++kk){
    int kb = k0 + kk*32;
    bf16x8 af[3], bv[3];
    #pragma unroll
    for (int i=0;i<3;++i){
      af[i] = ld_bf8(qbase + (size_t)(i*16+c16)*L + kb + g16*8);
      bv[i] = ld_bf8(kbse  + (size_t)(i*16+c16)*L + kb + g16*8);
    }
    #pragma unroll
    for (int mi=0;mi<3;++mi)
      #pragma unroll
      for (int ni=0;ni<3;++ni)
        acc[mi][ni] = mfma16(af[mi], bv[ni], acc[mi][ni]);
  }
  float* Pp = P + ((size_t)ks*(BATCH*NH) + bh)*CHN*CHN;
  #pragma unroll
  for (int mi=0;mi<3;++mi)
    #pragma unroll
    for (int ni=0;ni<3;++ni)
      #pragma unroll
      for (int r=0;r<4;++r){
        int m = mi*16 + g16*4 + r, n = ni*16 + c16;
        Pp[m*CHN + n] = acc[mi][ni][r];
      }
}

__global__ void reduceS_k(const float* __restrict__ P, float* __restrict__ S){
  int i = blockIdx.x*256 + threadIdx.x;
  if (i >= BATCH*NH*CHN*CHN) return;
  float s = 0.f;
  for (int ks=0; ks<KSPLIT; ++ks) s += P[(size_t)ks*(BATCH*NH*CHN*CHN) + i];
  S[i] = s;
}

// ---------------- softmax + gating + Wca modulation: one wave per (b,h,c) row ----------------
__global__ __launch_bounds__(64) void gating_k(const float* __restrict__ S, const float* __restrict__ qss,
                         const float* __restrict__ kss, const float* __restrict__ temp,
                         const float* __restrict__ Wca, float* __restrict__ attnF){
  int blk = blockIdx.x;                 // bh*CHN + c
  int c  = blk % CHN; int bh = blk / CHN;
  int h  = bh & 3, b = bh >> 2;
  int d  = threadIdx.x;                 // lane; active for d < 48
  bool act = (d < CHN);

  float T  = temp[h];
  float nq = sqrtf(qss[b*C0 + h*CHN + c]);
  float rq = 1.f/fmaxf(nq, 1e-12f);
  float rk = 0.f, sv = 0.f;
  if (act){
    float nk = sqrtf(kss[b*C0 + h*CHN + d]);
    rk = 1.f/fmaxf(nk, 1e-12f);
    sv = S[((size_t)bh*CHN + c)*CHN + d];
  }
  float raw = act ? sv*rq*rk*T : -1e30f;

  float mx = raw;
  #pragma unroll
  for (int off=32; off>0; off>>=1) mx = fmaxf(mx, __shfl_xor(mx, off, 64));
  float e = act ? expf(raw - mx) : 0.f;
  float sum = e;
  #pragma unroll
  for (int off=32; off>0; off>>=1) sum += __shfl_xor(sum, off, 64);
  float a0 = e / sum;

  float r = fmaxf(raw, 0.f); r = r*r;
  float a1 = gelu_exact(r)*r;
  __shared__ float a1s[CHN];
  if (act) a1s[d] = a1;
  __syncthreads();

  if (!act) return;
  float s1 = 0.f, s2 = 0.f;
  const float* w1 = Wca + (size_t)d*CHN;
  const float* w2 = Wca + (size_t)(d+CHN)*CHN;
  #pragma unroll
  for (int j=0;j<CHN;++j){
    float aj = a1s[j];
    s1 = fmaf(w1[j], aj, s1);
    s2 = fmaf(w2[j], aj, s2);
  }
  attnF[((size_t)bh*CHN + c)*CHN + d] = a0*(1.f+s1) + s2;
}

// Mtb[b][o][dfull] = sum_c Wproj[o][h*48+c] * attnF[b][h][c][d]   (bf16)
__global__ void mt_k(const float* __restrict__ Wproj, const float* __restrict__ attnF,
                     ushort* __restrict__ Mtb){
  int idx = blockIdx.x*256 + threadIdx.x;
  if (idx >= BATCH*C0*C0) return;
  int d = idx % C0; int o = (idx / C0) % C0; int b = idx / (C0*C0);
  int h = d / CHN, dd = d % CHN;
  float s=0.f;
  for (int c=0;c<CHN;++c)
    s = fmaf(Wproj[(size_t)o*C0 + h*CHN + c],
             attnF[(((size_t)(b*NH+h))*CHN + c)*CHN + dd], s);
  Mtb[idx] = f2u(s);
}

// ---------------- GDFN fused dwconv + gelu gate (writes 512 rows/b, pad rows zero) ----------------
__global__ __launch_bounds__(256) void ffn8_k(const ushort* __restrict__ hidden, const float* __restrict__ w9,
                                              ushort* __restrict__ g){
  int e  = blockIdx.x*256 + threadIdx.x;
  int bg = e >> 11;
  int p  = (e & 2047) * 8;
  int go = bg & 511, b = bg >> 9;
  ushort* op = g + (size_t)bg*L + p;
  if (go >= HID){ uint4 z = {0,0,0,0}; *(uint4*)op = z; return; }
  int y = p >> 7, x0 = p & 127;
  const ushort* i1 = hidden + ((size_t)b*HID2 + go)*L;
  const ushort* i2 = i1 + (size_t)HID*L;
  float w1[9], w2[9];
  #pragma unroll
  for (int i=0;i<9;++i){ w1[i] = w9[go*9+i]; w2[i] = w9[(HID+go)*9+i]; }
  float v1[3][10], v2[3][10];
  #pragma unroll
  for (int r=0;r<3;++r){
    int yy = y + r - 1;
    if ((unsigned)yy >= IMG){
      #pragma unroll
      for (int j=0;j<10;++j){ v1[r][j]=0.f; v2[r][j]=0.f; }
    } else {
      const ushort* rp1 = i1 + yy*IMG + x0;
      const ushort* rp2 = i2 + yy*IMG + x0;
      uint4 c1 = *(const uint4*)rp1; const ushort* u1 = (const ushort*)&c1;
      uint4 c2 = *(const uint4*)rp2; const ushort* u2 = (const ushort*)&c2;
      #pragma unroll
      for (int j=0;j<8;++j){ v1[r][j+1] = u2f(u1[j]); v2[r][j+1] = u2f(u2[j]); }
      v1[r][0] = (x0>0)   ? u2f(rp1[-1]) : 0.f;
      v1[r][9] = (x0<120) ? u2f(rp1[8])  : 0.f;
      v2[r][0] = (x0>0)   ? u2f(rp2[-1]) : 0.f;
      v2[r][9] = (x0<120) ? u2f(rp2[8])  : 0.f;
    }
  }
  ushort o8[8];
  #pragma unroll
  for (int j=0;j<8;++j){
    float d1=0.f, d2=0.f;
    #pragma unroll
    for (int r=0;r<3;++r)
      #pragma unroll
      for (int dx=0;dx<3;++dx){
        d1 = fmaf(w1[r*3+dx], v1[r][j+dx], d1);
        d2 = fmaf(w2[r*3+dx], v2[r][j+dx], d2);
      }
    o8[j] = f2u(gelu_exact(d1)*d2);
  }
  *(uint4*)op = *(const uint4*)o8;
}

extern "C" void kernel_launch(void* const* d_in, const int* in_sizes, int n_in,
                              void* d_out, int out_size, void* d_ws, size_t ws_size,
                              hipStream_t stream){
  (void)in_sizes; (void)n_in; (void)out_size; (void)ws_size;
  const float* lr    = (const float*)d_in[0];
  const float* ref   = (const float*)d_in[1];
  const float* ln1w  = (const float*)d_in[2];
  const float* ln1b  = (const float*)d_in[3];
  const float* lnrw  = (const float*)d_in[4];
  const float* lnrb  = (const float*)d_in[5];
  const float* ln2w  = (const float*)d_in[6];
  const float* ln2b  = (const float*)d_in[7];
  const float* Wq    = (const float*)d_in[8];
  const float* qdw   = (const float*)d_in[9];
  const float* Wkv   = (const float*)d_in[10];
  const float* kvdw  = (const float*)d_in[11];
  const float* Wproj = (const float*)d_in[12];
  const float* Wca   = (const float*)d_in[13];
  const float* temp  = (const float*)d_in[14];
  const float* Wpin  = (const float*)d_in[15];
  const float* ffndw = (const float*)d_in[16];
  const float* Wpout = (const float*)d_in[17];
  float* out = (float*)d_out;

  char* ws = (char*)d_ws;
  size_t off = 0;
  auto alloc = [&](size_t bytes)->void*{ void* p = ws + off; off += (bytes + 255) & ~(size_t)255; return p; };

  ushort* Aqbf   = (ushort*)alloc((size_t)192*192*2);
  ushort* Akvbf  = (ushort*)alloc((size_t)384*192*2);
  ushort* Apinbf = (ushort*)alloc((size_t)1024*192*2);
  ushort* Apoutbf= (ushort*)alloc((size_t)192*512*2);
  ushort* Mtb    = (ushort*)alloc((size_t)BATCH*C0*C0*2);
  float* Aqv  = (float*)alloc(192*4);   float* Bqv  = (float*)alloc(192*4);
  float* Akvv = (float*)alloc(384*4);   float* Bkvv = (float*)alloc(384*4);
  float* Apinv= (float*)alloc(1024*4);  float* Bpinv= (float*)alloc(1024*4);
  float* mu_lr = (float*)alloc((size_t)BL*4);  float* rs_lr = (float*)alloc((size_t)BL*4);
  float* mu_rf = (float*)alloc((size_t)BL*4);  float* rs_rf = (float*)alloc((size_t)BL*4);
  float* mu_o  = (float*)alloc((size_t)BL*4);  float* rs_o  = (float*)alloc((size_t)BL*4);
  float* qss   = (float*)alloc((size_t)BATCH*C0*4);
  float* kss   = (float*)alloc((size_t)BATCH*C0*4);
  float* S     = (float*)alloc((size_t)BATCH*NH*CHN*CHN*4);
  float* attnF = (float*)alloc((size_t)BATCH*NH*CHN*CHN*4);
  char*  pool  = (char*)alloc((size_t)109051904);

  ushort* q_pre  = (ushort*)(pool);                       // 12,582,912
  ushort* kv_pre = (ushort*)(pool + 12582912);            // 25,165,824
  ushort* qb     = (ushort*)(pool + 37748736);            // 12,582,912
  ushort* kvb    = (ushort*)(pool + 50331648);            // 25,165,824
  float*  Pp     = (float*) (pool);                       // overlays q_pre/kv_pre (dead then)
  ushort* hidden = (ushort*)(pool);                       // 66,846,720 (overlays first 4, dead then)
  ushort* g      = (ushort*)(pool + 75497472);            // 33,554,432

  hipMemsetAsync(qss, 0, (size_t)BATCH*C0*4, stream);
  hipMemsetAsync(kss, 0, (size_t)BATCH*C0*4, stream);

  // weight prep
  packw_k<<<(192*192+255)/256,256,0,stream>>>(Wq,   ln1w, Aqbf,   192, 192, 192, 192*192);
  packw_k<<<(384*192+255)/256,256,0,stream>>>(Wkv,  lnrw, Akvbf,  192, 384, 192, 384*192);
  packw_k<<<(1024*192+255)/256,256,0,stream>>>(Wpin, ln2w, Apinbf, 192, 1020, 192, 1024*192);
  packw_k<<<(192*512+255)/256,256,0,stream>>>(Wpout, nullptr, Apoutbf, 510, 192, 512, 192*512);
  prepab_k<<<1,256,0,stream>>>(Wq,  ln1w, ln1b, Aqv,  Bqv,  192, 192, 192);
  prepab_k<<<2,256,0,stream>>>(Wkv, lnrw, lnrb, Akvv, Bkvv, 192, 384, 384);
  prepab_k<<<4,256,0,stream>>>(Wpin,ln2w, ln2b, Apinv,Bpinv,192, 1020, 1024);

  // LN stats
  ln_stats_k<<<BL/256,256,0,stream>>>(lr,  mu_lr, rs_lr);
  ln_stats_k<<<BL/256,256,0,stream>>>(ref, mu_rf, rs_rf);

  // fused LN + 1x1 conv GEMMs (pipelined MFMA)
  gemm2_k<0,1,192,true><<<dim3(256,3),256,0,stream>>>(Aqbf, 0, lr, (size_t)C0*L,
      mu_lr, rs_lr, Aqv, Bqv, nullptr, q_pre, 192, 192);
  gemm2_k<0,2,192,true><<<dim3(256,3),256,0,stream>>>(Akvbf, 0, ref, (size_t)C0*L,
      mu_rf, rs_rf, Akvv, Bkvv, nullptr, kv_pre, 384, 384);

  // depthwise convs + l2 sum-of-squares
  dwconv8_k<<<(BATCH*192*L/8)/256,256,0,stream>>>(q_pre,  qdw,  qb,  qss, 192, 192);
  dwconv8_k<<<(BATCH*384*L/8)/256,256,0,stream>>>(kv_pre, kvdw, kvb, kss, 384, 192);

  // attention core
  qk_mfma_k<<<dim3(KSPLIT, BATCH*NH),64,0,stream>>>(qb, kvb, Pp);
  reduceS_k<<<(BATCH*NH*CHN*CHN+255)/256,256,0,stream>>>(Pp, S);
  gating_k<<<BATCH*NH*CHN,64,0,stream>>>(S, qss, kss, temp, Wca, attnF);
  mt_k<<<(BATCH*C0*C0+255)/256,256,0,stream>>>(Wproj, attnF, Mtb);

  // out = lr + Mt . v
  gemm2_k<1,1,192,false><<<dim3(256,3),256,0,stream>>>(Mtb, 192*192, kvb + (size_t)C0*L, (size_t)2*C0*L,
      nullptr, nullptr, nullptr, nullptr, lr, out, 192, 192);

  // GDFN
  ln_stats_k<<<BL/256,256,0,stream>>>(out, mu_o, rs_o);
  gemm2_k<0,2,192,true><<<dim3(256,8),256,0,stream>>>(Apinbf, 0, out, (size_t)C0*L,
      mu_o, rs_o, Apinv, Bpinv, nullptr, hidden, 1020, 1020);
  ffn8_k<<<(BATCH*512*L/8)/256,256,0,stream>>>(hidden, ffndw, g);
  gemm2_k<2,1,512,false><<<dim3(256,3),256,0,stream>>>(Apoutbf, 0, g, (size_t)512*L,
      nullptr, nullptr, nullptr, nullptr, nullptr, out, 192, 192);
}